// Round 4
// baseline (27389.877 us; speedup 1.0000x reference)
//
#include <hip/hip_runtime.h>
#include <hip/hip_bf16.h>

typedef __hip_bfloat16 bf16;

#define SB 2
#define SS 2048
#define SD 512
#define SH 8
#define SWIN 128
#define SCH 64
#define SNCH 32
#define SFF 2048
#define KPROWS 2176              // WIN + S
#define KPBATCH 1114112L         // KPROWS*SD
#define BSD 1048576L             // SS*SD
#define DD 262144L               // SD*SD

__device__ __forceinline__ float ldf(const float* p){ return *p; }
__device__ __forceinline__ void stf(float* p, float v){ *p = v; }
__device__ __forceinline__ void stf(bf16* p, float v){ *p = __float2bfloat16(v); }

__device__ __forceinline__ float block_sum256(float v, float* sbuf){
  #pragma unroll
  for (int o = 32; o > 0; o >>= 1) v += __shfl_xor(v, o);
  int wid = threadIdx.x >> 6;
  if ((threadIdx.x & 63) == 0) sbuf[wid] = v;
  __syncthreads();
  float r = sbuf[0] + sbuf[1] + sbuf[2] + sbuf[3];
  __syncthreads();
  return r;
}

enum { EPI_NONE=0, EPI_SILU=1, EPI_SUB=2, EPI_LINCOMB=3, EPI_MUL=4, EPI_ADD=5, EPI_SILU_MUL=6 };

// C[M,N] = op(A) @ op(B) (+epilogue).  TRA: A is [K,M] accessed A[k*lda+m].
// TRB=true: B is [N,K] (i.e. @ W.T). Batched via blockIdx.z with strides.
template<int BM, int BN, bool TRA, bool TRB, int EPI, typename TO>
__global__ __launch_bounds__(256)
void gemm_k(const float* __restrict__ Ag, const float* __restrict__ Bg, TO* __restrict__ Cg,
            const float* __restrict__ Eg, float a0, float a1,
            int M, int N, int K,
            long sA, long sB, long sC, long sE,
            int lda, int ldb, int ldc, int lde)
{
  constexpr int BK = 16;
  constexpr int TM = BM/16, TN = BN/16;
  __shared__ float As[BK][BM+1];
  __shared__ float Bs[BK][BN+1];
  const int bz = blockIdx.z;
  const float* A = Ag + (long)bz*sA;
  const float* Bp = Bg + (long)bz*sB;
  TO* C = Cg + (long)bz*sC;
  const float* E = Eg ? (Eg + (long)bz*sE) : nullptr;
  const int bm = blockIdx.x*BM, bn = blockIdx.y*BN;
  const int tid = threadIdx.x;
  const int tx = tid & 15, ty = tid >> 4;
  float acc[TM][TN];
  #pragma unroll
  for (int i=0;i<TM;i++)
    #pragma unroll
    for (int j=0;j<TN;j++) acc[i][j]=0.f;

  for (int k0 = 0; k0 < K; k0 += BK) {
    for (int e = tid; e < BM*BK; e += 256) {
      int m, kk;
      if (TRA) { m = e % BM; kk = e / BM; } else { kk = e % BK; m = e / BK; }
      int gm = bm + m, gk = k0 + kk;
      float v = 0.f;
      if (gm < M) v = TRA ? ldf(&A[(long)gk*lda + gm]) : ldf(&A[(long)gm*lda + gk]);
      As[kk][m] = v;
    }
    for (int e = tid; e < BN*BK; e += 256) {
      int nn, kk;
      if (TRB) { kk = e % BK; nn = e / BK; } else { nn = e % BN; kk = e / BN; }
      int gn = bn + nn, gk = k0 + kk;
      float v = 0.f;
      if (gn < N) v = TRB ? ldf(&Bp[(long)gn*ldb + gk]) : ldf(&Bp[(long)gk*ldb + gn]);
      Bs[kk][nn] = v;
    }
    __syncthreads();
    #pragma unroll
    for (int kk = 0; kk < BK; kk++) {
      float a[TM], bv[TN];
      #pragma unroll
      for (int i=0;i<TM;i++) a[i] = As[kk][ty*TM+i];
      #pragma unroll
      for (int j=0;j<TN;j++) bv[j] = Bs[kk][tx*TN+j];
      #pragma unroll
      for (int i=0;i<TM;i++)
        #pragma unroll
        for (int j=0;j<TN;j++)
          acc[i][j] += a[i]*bv[j];
    }
    __syncthreads();
  }

  #pragma unroll
  for (int i=0;i<TM;i++) {
    int row = bm + ty*TM + i;
    if (row >= M) continue;
    #pragma unroll
    for (int j=0;j<TN;j++) {
      int col = bn + tx*TN + j;
      if (col >= N) continue;
      float v = acc[i][j];
      if (EPI == EPI_SILU)          v = v / (1.f + __expf(-v));
      else if (EPI == EPI_SUB)      v = v - E[(long)row*lde + col];
      else if (EPI == EPI_LINCOMB)  v = a0*E[(long)row*lde + col] + a1*v;
      else if (EPI == EPI_MUL)      v = v * E[(long)row*lde + col];
      else if (EPI == EPI_ADD)      v = v + E[(long)row*lde + col];
      else if (EPI == EPI_SILU_MUL) v = (v / (1.f + __expf(-v))) * E[(long)row*lde + col];
      stf(&C[(long)row*ldc + col], v);
    }
  }
}

// xn = x * nw * rsqrt(mean(x^2)+eps); one block per row
__global__ __launch_bounds__(256) void rmsnorm_in_k(const float* __restrict__ x,
    const float* __restrict__ w, float* __restrict__ xn)
{
  __shared__ float sbuf[4];
  long row = blockIdx.x;
  const float* xr = x + row*SD;
  int c0 = threadIdx.x, c1 = threadIdx.x + 256;
  float v0 = xr[c0], v1 = xr[c1];
  float ss = block_sum256(v0*v0 + v1*v1, sbuf);
  float r = rsqrtf(ss*(1.f/SD) + 1e-6f);
  xn[row*SD + c0] = v0*r*w[c0];
  xn[row*SD + c1] = v1*r*w[c1];
}

// dst_row = rms(silu(dwconv3(raw_row))) * nw ;  one block per (t, b)
__global__ __launch_bounds__(256) void conv_silu_rms_k(const float* __restrict__ raw,
    const float* __restrict__ cw, const float* __restrict__ cb, const float* __restrict__ nw,
    float* __restrict__ dst, long dstBatchStride, int dstRowOff)
{
  __shared__ float sbuf[4];
  int t = blockIdx.x, b = blockIdx.y;
  const float* base = raw + ((long)b*SS + t)*SD;
  float vals[2];
  #pragma unroll
  for (int u = 0; u < 2; u++) {
    int c = threadIdx.x + u*256;
    float w0 = cw[c*3+0], w1 = cw[c*3+1], w2 = cw[c*3+2];
    float acc = cb[c];
    if (t > 0)     acc += base[c - SD]*w0;
    acc += base[c]*w1;
    if (t < SS-1)  acc += base[c + SD]*w2;
    vals[u] = acc / (1.f + __expf(-acc));
  }
  float ss = block_sum256(vals[0]*vals[0] + vals[1]*vals[1], sbuf);
  float r = rsqrtf(ss*(1.f/SD) + 1e-6f);
  float* out = dst + (long)b*dstBatchStride + (long)(dstRowOff + t)*SD;
  out[threadIdx.x]       = vals[0]*r*nw[threadIdx.x];
  out[threadIdx.x + 256] = vals[1]*r*nw[threadIdx.x + 256];
}

// per-(b,chunk) column means of a [B*S, 512] buffer -> [B*NCH, 512]
__global__ __launch_bounds__(256) void chunk_means1_k(const float* __restrict__ src,
    float* __restrict__ dst)
{
  int cb = blockIdx.x;          // b*32 + chunk
  long rowbase = (long)cb*SCH*SD;
  #pragma unroll
  for (int u = 0; u < 2; u++) {
    int col = threadIdx.x + u*256;
    float s = 0.f;
    for (int r = 0; r < SCH; r++) s += src[rowbase + (long)r*SD + col];
    dst[(long)cb*SD + col] = s * (1.f/SCH);
  }
}

__global__ __launch_bounds__(256) void frob_partial_k(const float* __restrict__ X,
    float* __restrict__ part)
{
  __shared__ float sbuf[4];
  int b = blockIdx.y;
  const float* base = X + (long)b*DD + (long)blockIdx.x*8192;
  float s = 0.f;
  for (int i = threadIdx.x; i < 8192; i += 256) { float v = base[i]; s += v*v; }
  s = block_sum256(s, sbuf);
  if (threadIdx.x == 0) part[b*32 + blockIdx.x] = s;
}

__global__ __launch_bounds__(256) void ns_scale_k(float* __restrict__ X,
    const float* __restrict__ part)
{
  int b = blockIdx.y;
  float s = 0.f;
  for (int i = 0; i < 32; i++) s += part[b*32 + i];
  float scale = 1.f / (sqrtf(s) + 1e-7f);
  long base = (long)b*DD + (long)blockIdx.x*4096;
  for (int i = threadIdx.x; i < 4096; i += 256) X[base + i] *= scale;
}

// M[b,i,j] = M[b,i,j]*alphaM[b,chunk,j] - X[b,i,j]*etaM[b,chunk,j]
__global__ __launch_bounds__(256) void update_M_k(float* __restrict__ M,
    const float* __restrict__ X, const float* __restrict__ etaM,
    const float* __restrict__ alphaM, int chunk)
{
  long idx = (long)blockIdx.x*256 + threadIdx.x;   // 524288 total
  int b = (int)(idx >> 18);
  int col = (int)(idx & (SD-1));
  long mo = ((long)(b*32 + chunk) << 9) + col;
  float al = alphaM[mo], et = etaM[mo];
  M[idx] = M[idx]*al - X[idx]*et;
}

// atlas epilogue (in place): t = rms(a)*nw_out*gb; a = rms(t)*n1_w
__global__ __launch_bounds__(256) void atlas_final_norm_k(float* __restrict__ a,
    const float* __restrict__ gb, const float* __restrict__ nwout,
    const float* __restrict__ n1w)
{
  __shared__ float sbuf[4];
  long row = blockIdx.x;
  float* xr = a + row*SD;
  int c0 = threadIdx.x, c1 = threadIdx.x + 256;
  float v0 = xr[c0], v1 = xr[c1];
  float ss = block_sum256(v0*v0 + v1*v1, sbuf);
  float r = rsqrtf(ss*(1.f/SD) + 1e-6f);
  float t0 = v0*r*nwout[c0] * gb[row*SD+c0];
  float t1 = v1*r*nwout[c1] * gb[row*SD+c1];
  float ss2 = block_sum256(t0*t0 + t1*t1, sbuf);
  float r2 = rsqrtf(ss2*(1.f/SD) + 1e-6f);
  xr[c0] = t0*r2*n1w[c0];
  xr[c1] = t1*r2*n1w[c1];
}

// dst = rms(o)*w + dst  (in place on dst)
__global__ __launch_bounds__(256) void rms_add_k(const float* __restrict__ o,
    const float* __restrict__ w, float* __restrict__ dst)
{
  __shared__ float sbuf[4];
  long row = blockIdx.x;
  const float* xr = o + row*SD;
  int c0 = threadIdx.x, c1 = threadIdx.x + 256;
  float v0 = xr[c0], v1 = xr[c1];
  float ss = block_sum256(v0*v0 + v1*v1, sbuf);
  float r = rsqrtf(ss*(1.f/SD) + 1e-6f);
  dst[row*SD+c0] += v0*r*w[c0];
  dst[row*SD+c1] += v1*r*w[c1];
}

// sliding-window attention, one wave per (b, h, query); 4 waves/block
__global__ __launch_bounds__(256) void attn_swa_k(const float* __restrict__ Q,
    const float* __restrict__ K, const float* __restrict__ V, float* __restrict__ O)
{
  __shared__ float sc[4][SWIN];
  int wid = threadIdx.x >> 6, lane = threadIdx.x & 63;
  int w = blockIdx.x*4 + wid;           // [0, B*H*S)
  int b = w >> 14;                       // / (H*S)
  int rem = w & 16383;
  int h = rem >> 11;                     // / S
  int i = rem & (SS-1);
  const float* qp = Q + ((long)b*SS + i)*SD + h*64;
  float qv = qp[lane];
  int j0 = i - (SWIN-1); if (j0 < 0) j0 = 0;
  int cnt = i - j0 + 1;
  const float* Kb = K + (long)b*SS*SD + h*64;
  const float* Vb = V + (long)b*SS*SD + h*64;
  float mx = -1e30f;
  for (int jj = 0; jj < cnt; jj++) {
    float p = qv * Kb[(long)(j0+jj)*SD + lane];
    #pragma unroll
    for (int o2 = 32; o2 > 0; o2 >>= 1) p += __shfl_xor(p, o2);
    p *= 0.125f;                         // 1/sqrt(64)
    if (lane == 0) sc[wid][jj] = p;
    mx = fmaxf(mx, p);
  }
  __syncthreads();
  float sum = 0.f, oa = 0.f;
  for (int jj = 0; jj < cnt; jj++) {
    float p = __expf(sc[wid][jj] - mx);
    sum += p;
    oa += p * Vb[(long)(j0+jj)*SD + lane];
  }
  O[((long)b*SS + i)*SD + h*64 + lane] = oa / sum;
}

__global__ __launch_bounds__(256) void copy_f_k(float* __restrict__ dst, long dstride,
    const float* __restrict__ src, long sstride, long nper, int nb)
{
  long total = nper * nb;
  for (long i = (long)blockIdx.x*256 + threadIdx.x; i < total; i += (long)gridDim.x*256) {
    long b = i / nper, r = i - b*nper;
    dst[b*dstride + r] = src[b*sstride + r];
  }
}

extern "C" void kernel_launch(void* const* d_in, const int* in_sizes, int n_in,
                              void* d_out, int out_size, void* d_ws, size_t ws_size,
                              hipStream_t stream)
{
  (void)in_sizes; (void)n_in; (void)out_size; (void)ws_size;
  const float* x      = (const float*)d_in[0];
  const float* mem0   = (const float*)d_in[1];
  const float* buf_k  = (const float*)d_in[2];
  const float* buf_v  = (const float*)d_in[3];
  const float* nw_in  = (const float*)d_in[4];
  const float* nw_kq  = (const float*)d_in[5];
  const float* nw_out = (const float*)d_in[6];
  const float* wk_a   = (const float*)d_in[7];
  const float* wq_a   = (const float*)d_in[8];
  const float* wv_a   = (const float*)d_in[9];
  const float* wg     = (const float*)d_in[10];
  const float* wb     = (const float*)d_in[11];
  const float* ck_w   = (const float*)d_in[12];
  const float* ck_b   = (const float*)d_in[13];
  const float* cq_w   = (const float*)d_in[14];
  const float* cq_b   = (const float*)d_in[15];
  const float* s1_wq  = (const float*)d_in[16];
  const float* s1_wk  = (const float*)d_in[17];
  const float* s1_wv  = (const float*)d_in[18];
  const float* s1_wo  = (const float*)d_in[19];
  const float* s2_wq  = (const float*)d_in[20];
  const float* s2_wk  = (const float*)d_in[21];
  const float* s2_wv  = (const float*)d_in[22];
  const float* s2_wo  = (const float*)d_in[23];
  const float* n1_w   = (const float*)d_in[24];
  const float* n2_w   = (const float*)d_in[25];
  const float* m_w1   = (const float*)d_in[26];
  const float* m_w2   = (const float*)d_in[27];
  const float* m_w3   = (const float*)d_in[28];
  float* ob = (float*)d_out;   // output dtype = reference output dtype = float32

  // ---- workspace carve: 15,728,704 floats = 60.0 MB ----
  float* p = (float*)d_ws;
  float* kp   = p; p += SB*KPBATCH;   // padded k [B,2176,512]; C: attn out; MLP: h1 head
  float* vp   = p; p += SB*KPBATCH;   // padded v; C: oproj1 out; MLP: h1
  float* qbuf = p; p += SB*BSD;       // atlas q; C: v1/v2; MLP: h1
  float* gb   = p; p += SB*BSD;       // gamma*bypass; C: k1/k2; MLP: h1 tail
  float* sc1  = p; p += SB*BSD;       // xn; C: q1/q2, y
  float* sc2  = p; p += SB*BSD;       // kraw/qraw; B: aout; C: memn->fused
  float* Mb   = p; p += SB*DD;        // (Mb..Am also = nsbuf for eta/alpha gemms)
  float* X0   = p; p += SB*DD;
  float* X1   = p; p += SB*DD;
  float* Am   = p; p += SB*DD;
  float* Tm   = p; p += SB*DD;
  float* err  = p; p += (long)SB*(SWIN+SCH)*SD;
  float* etaM = p; p += (long)SB*SNCH*SD;
  float* alphaM = p; p += (long)SB*SNCH*SD;
  float* partials = p; p += 64;
  float* nsbuf = Mb;                  // 4*DD = 2,097,152 floats, phase-A only
  float* aout = sc2;
  float* hbuf = kp;                   // MLP h1/h2: kp..gb span (8,650,752 >= 8,388,608)

  dim3 blk(256);

  // ================= Phase A =================
  rmsnorm_in_k<<<SB*SS, blk, 0, stream>>>(x, nw_in, sc1);

  // v = silu(xn @ wv_a.T) -> vp interior
  gemm_k<64,64,false,true,EPI_SILU,float><<<dim3(32,8,2),blk,0,stream>>>(
      sc1, wv_a, vp + (long)SWIN*SD, nullptr, 0.f,0.f, SS, SD, SD,
      BSD, 0, KPBATCH, 0, SD, SD, SD, 0);

  // k path: proj -> sc2 ; conv+silu+rms -> kp interior
  gemm_k<64,64,false,true,EPI_NONE,float><<<dim3(64,8,1),blk,0,stream>>>(
      sc1, wk_a, sc2, nullptr, 0.f,0.f, SB*SS, SD, SD, 0,0,0,0, SD,SD,SD,0);
  conv_silu_rms_k<<<dim3(SS,SB),blk,0,stream>>>(sc2, ck_w, ck_b, nw_kq, kp, KPBATCH, SWIN);

  // q path -> qbuf
  gemm_k<64,64,false,true,EPI_NONE,float><<<dim3(64,8,1),blk,0,stream>>>(
      sc1, wq_a, sc2, nullptr, 0.f,0.f, SB*SS, SD, SD, 0,0,0,0, SD,SD,SD,0);
  conv_silu_rms_k<<<dim3(SS,SB),blk,0,stream>>>(sc2, cq_w, cq_b, nw_kq, qbuf, BSD, 0);

  // gamma = silu(xn @ wg[0:512].T) -> gb; then gb = silu(xn @ wb.T) * gb
  gemm_k<64,64,false,true,EPI_SILU,float><<<dim3(64,8,1),blk,0,stream>>>(
      sc1, wg, gb, nullptr, 0.f,0.f, SB*SS, SD, SD, 0,0,0,0, SD,SD,SD,0);
  gemm_k<64,64,false,true,EPI_SILU_MUL,float><<<dim3(64,8,1),blk,0,stream>>>(
      sc1, wb, gb, gb, 0.f,0.f, SB*SS, SD, SD, 0,0,0,0, SD,SD,SD,SD);

  // eta means: silu(xn @ wg[512:1024].T) -> nsbuf -> etaM
  gemm_k<64,64,false,true,EPI_SILU,float><<<dim3(64,8,1),blk,0,stream>>>(
      sc1, wg + (long)SD*SD, nsbuf, nullptr, 0.f,0.f, SB*SS, SD, SD, 0,0,0,0, SD,SD,SD,0);
  chunk_means1_k<<<SB*SNCH, blk, 0, stream>>>(nsbuf, etaM);
  // alpha means
  gemm_k<64,64,false,true,EPI_SILU,float><<<dim3(64,8,1),blk,0,stream>>>(
      sc1, wg + 2L*SD*SD, nsbuf, nullptr, 0.f,0.f, SB*SS, SD, SD, 0,0,0,0, SD,SD,SD,0);
  chunk_means1_k<<<SB*SNCH, blk, 0, stream>>>(nsbuf, alphaM);

  // heads of kp/vp; M init (AFTER nsbuf use — Mb aliases nsbuf)
  copy_f_k<<<256,blk,0,stream>>>(kp, KPBATCH, buf_k, (long)SWIN*SD, (long)SWIN*SD, SB);
  copy_f_k<<<256,blk,0,stream>>>(vp, KPBATCH, buf_v, (long)SWIN*SD, (long)SWIN*SD, SB);
  copy_f_k<<<256,blk,0,stream>>>(Mb, DD, mem0, DD, DD, SB);

  // ================= Phase B: sequential chunk scan =================
  for (int t = 0; t < SNCH; ++t) {
    const float* ck = kp + (long)t*SCH*SD;
    const float* cv = vp + (long)t*SCH*SD;
    // err = ctx_k @ M - ctx_v   [b,192,512]
    gemm_k<32,32,false,false,EPI_SUB,float><<<dim3(6,16,2),blk,0,stream>>>(
        ck, Mb, err, cv, 0.f,0.f, SWIN+SCH, SD, SD,
        KPBATCH, DD, (long)(SWIN+SCH)*SD, KPBATCH, SD, SD, SD, SD);
    // grad = ctx_k^T @ err -> X0
    gemm_k<32,32,true,false,EPI_NONE,float><<<dim3(16,16,2),blk,0,stream>>>(
        ck, err, X0, nullptr, 0.f,0.f, SD, SD, SWIN+SCH,
        KPBATCH, (long)(SWIN+SCH)*SD, DD, 0, SD, SD, SD, 0);
    // X0 /= (||G||_F + 1e-7)
    frob_partial_k<<<dim3(32,2),blk,0,stream>>>(X0, partials);
    ns_scale_k<<<dim3(64,2),blk,0,stream>>>(X0, partials);
    // 5 Newton-Schulz iterations
    float* Xc = X0; float* Xn = X1;
    for (int it = 0; it < 5; ++it) {
      gemm_k<32,32,false,true,EPI_NONE,float><<<dim3(16,16,2),blk,0,stream>>>(
          Xc, Xc, Am, nullptr, 0.f,0.f, SD,SD,SD, DD,DD,DD,0, SD,SD,SD,0);
      gemm_k<32,32,false,false,EPI_LINCOMB,float><<<dim3(16,16,2),blk,0,stream>>>(
          Am, Am, Tm, Am, -4.7750f, 2.0315f, SD,SD,SD, DD,DD,DD,DD, SD,SD,SD,SD);
      gemm_k<32,32,false,false,EPI_LINCOMB,float><<<dim3(16,16,2),blk,0,stream>>>(
          Tm, Xc, Xn, Xc, 3.4445f, 1.0f, SD,SD,SD, DD,DD,DD,DD, SD,SD,SD,SD);
      float* tmp = Xc; Xc = Xn; Xn = tmp;
    }
    // M = M*alpha_mean - og*eta_mean
    update_M_k<<<2048,blk,0,stream>>>(Mb, Xc, etaM, alphaM, t);
    // out_chunk = cq @ M -> aout(=sc2)
    gemm_k<32,32,false,false,EPI_NONE,float><<<dim3(2,16,2),blk,0,stream>>>(
        qbuf + (long)t*SCH*SD, Mb, aout + (long)t*SCH*SD, nullptr, 0.f,0.f,
        SCH, SD, SD, BSD, DD, BSD, 0, SD, SD, SD, 0);
  }

  // ================= Phase C =================
  // mem_normed in place into sc2
  atlas_final_norm_k<<<SB*SS,blk,0,stream>>>(sc2, gb, nw_out, n1_w);

  // side outputs now (frees kp/vp/Mb for reuse) — f32 copies into f32 d_out
  copy_f_k<<<256,blk,0,stream>>>(ob + (long)SB*SS*SD, DD, Mb, DD, DD, SB);
  copy_f_k<<<256,blk,0,stream>>>(ob + (long)SB*SS*SD + SB*DD, (long)SWIN*SD,
      kp + (long)SS*SD, KPBATCH, (long)SWIN*SD, SB);
  copy_f_k<<<256,blk,0,stream>>>(ob + (long)SB*SS*SD + SB*DD + (long)SB*SWIN*SD, (long)SWIN*SD,
      vp + (long)SS*SD, KPBATCH, (long)SWIN*SD, SB);

  // SWA 1 on x: q->sc1, k->gb, v->qbuf; attn->kp; oproj->vp; fused: sc2 += rms(vp)*n2
  gemm_k<64,64,false,true,EPI_NONE,float><<<dim3(64,8,1),blk,0,stream>>>(
      x, s1_wq, sc1, nullptr,0.f,0.f, SB*SS, SD, SD, 0,0,0,0, SD,SD,SD,0);
  gemm_k<64,64,false,true,EPI_NONE,float><<<dim3(64,8,1),blk,0,stream>>>(
      x, s1_wk, gb, nullptr,0.f,0.f, SB*SS, SD, SD, 0,0,0,0, SD,SD,SD,0);
  gemm_k<64,64,false,true,EPI_NONE,float><<<dim3(64,8,1),blk,0,stream>>>(
      x, s1_wv, qbuf, nullptr,0.f,0.f, SB*SS, SD, SD, 0,0,0,0, SD,SD,SD,0);
  attn_swa_k<<<SB*SH*SS/4, blk, 0, stream>>>(sc1, gb, qbuf, kp);
  gemm_k<64,64,false,true,EPI_NONE,float><<<dim3(64,8,1),blk,0,stream>>>(
      kp, s1_wo, vp, nullptr,0.f,0.f, SB*SS, SD, SD, 0,0,0,0, SD,SD,SD,0);
  rms_add_k<<<SB*SS,blk,0,stream>>>(vp, n2_w, sc2);   // sc2 = fused

  // SWA 2 on fused(sc2): q->sc1, k->gb, v->qbuf; attn->kp; y->sc1
  gemm_k<64,64,false,true,EPI_NONE,float><<<dim3(64,8,1),blk,0,stream>>>(
      sc2, s2_wq, sc1, nullptr,0.f,0.f, SB*SS, SD, SD, 0,0,0,0, SD,SD,SD,0);
  gemm_k<64,64,false,true,EPI_NONE,float><<<dim3(64,8,1),blk,0,stream>>>(
      sc2, s2_wk, gb, nullptr,0.f,0.f, SB*SS, SD, SD, 0,0,0,0, SD,SD,SD,0);
  gemm_k<64,64,false,true,EPI_NONE,float><<<dim3(64,8,1),blk,0,stream>>>(
      sc2, s2_wv, qbuf, nullptr,0.f,0.f, SB*SS, SD, SD, 0,0,0,0, SD,SD,SD,0);
  attn_swa_k<<<SB*SH*SS/4, blk, 0, stream>>>(sc1, gb, qbuf, kp);
  gemm_k<64,64,false,true,EPI_NONE,float><<<dim3(64,8,1),blk,0,stream>>>(
      kp, s2_wo, sc1, nullptr,0.f,0.f, SB*SS, SD, SD, 0,0,0,0, SD,SD,SD,0); // y=sc1

  // MLP: h1 = silu(y@w1.T) -> hbuf(kp..gb span); h2 = (y@w2.T)*h1 in place;
  // out = h2@w3.T + fused(sc2) -> ob (f32)
  gemm_k<64,64,false,true,EPI_SILU,float><<<dim3(64,32,1),blk,0,stream>>>(
      sc1, m_w1, hbuf, nullptr,0.f,0.f, SB*SS, SFF, SD, 0,0,0,0, SD,SD,SFF,0);
  gemm_k<64,64,false,true,EPI_MUL,float><<<dim3(64,32,1),blk,0,stream>>>(
      sc1, m_w2, hbuf, hbuf, 0.f,0.f, SB*SS, SFF, SD, 0,0,0,0, SD,SD,SFF,SFF);
  gemm_k<64,64,false,true,EPI_ADD,float><<<dim3(64,8,1),blk,0,stream>>>(
      hbuf, m_w3, ob, sc2, 0.f,0.f, SB*SS, SD, SFF, 0,0,0,0, SFF,SFF,SD,SD);
}

// Round 6
// 12299.536 us; speedup vs baseline: 2.2269x; 2.2269x over previous
//
#include <hip/hip_runtime.h>
#include <hip/hip_bf16.h>

typedef __hip_bfloat16 bf16;
typedef __attribute__((ext_vector_type(8))) short bfrag;   // 8 bf16 = 4 VGPRs
typedef __attribute__((ext_vector_type(4))) float f32x4;

#define SB 2
#define SS 2048
#define SD 512
#define SH 8
#define SWIN 128
#define SCH 64
#define SNCH 32
#define SFF 2048
#define KPROWS 2176              // WIN + S
#define KPBATCH 1114112L         // KPROWS*SD
#define BSD 1048576L             // SS*SD
#define DD 262144L               // SD*SD

__device__ __forceinline__ void stf(float* p, float v){ *p = v; }
__device__ __forceinline__ void stf(bf16* p, float v){ *p = __float2bfloat16(v); }

// f32 -> bf16 bits, round-to-nearest-even (finite inputs)
__device__ __forceinline__ unsigned short f2bs(float f){
  union { float f; unsigned int u; } v; v.f = f;
  unsigned int r = v.u + 0x7FFFu + ((v.u >> 16) & 1u);
  return (unsigned short)(r >> 16);
}
__device__ __forceinline__ float bs2f(unsigned short h){
  union { unsigned int u; float f; } v; v.u = ((unsigned int)h) << 16;
  return v.f;
}

__device__ __forceinline__ float block_sum256(float v, float* sbuf){
  #pragma unroll
  for (int o = 32; o > 0; o >>= 1) v += __shfl_xor(v, o);
  int wid = threadIdx.x >> 6;
  if ((threadIdx.x & 63) == 0) sbuf[wid] = v;
  __syncthreads();
  float r = sbuf[0] + sbuf[1] + sbuf[2] + sbuf[3];
  __syncthreads();
  return r;
}

enum { EPI_NONE=0, EPI_SILU=1, EPI_SUB=2, EPI_LINCOMB=3, EPI_MUL=4, EPI_ADD=5, EPI_SILU_MUL=6 };

// Split-bf16 (Dekker) MFMA GEMM: C = op(A) @ op(B) (+epilogue), f32 in/out.
// Each operand split hi+lo bf16; product via 3 MFMA passes (hi*hi + hi*lo + lo*hi),
// f32 accumulate -> ~1.5e-5 relative error (f32-grade for this net).
// TRA: A is [K,M]. TRB: B is [N,K]. Requires M%64==N%64==K%32==0.
template<bool TRA, bool TRB, int EPI, typename TO>
__global__ __launch_bounds__(256)
void mgemm_k(const float* __restrict__ Ag, const float* __restrict__ Bg, TO* __restrict__ Cg,
             const float* __restrict__ Eg, float a0, float a1,
             int M, int N, int K,
             long sA, long sB, long sC, long sE,
             int lda, int ldb, int ldc, int lde)
{
  __shared__ __align__(16) unsigned short As[2][64][40];  // [hi/lo][m][k], +8 pad
  __shared__ __align__(16) unsigned short Bs[2][64][40];  // [hi/lo][n][k]
  const int bz = blockIdx.z;
  const float* A = Ag + (long)bz*sA;
  const float* Bp = Bg + (long)bz*sB;
  TO* C = Cg + (long)bz*sC;
  const float* E = Eg ? (Eg + (long)bz*sE) : nullptr;
  const int bm = blockIdx.x*64, bn = blockIdx.y*64;
  const int tid = threadIdx.x;
  const int lane = tid & 63, wid = tid >> 6;
  const int wr = (wid >> 1)*32, wc = (wid & 1)*32;   // wave quadrant
  const int fm = lane & 15, fk = (lane >> 4)*8;      // fragment row + k offset

  f32x4 acc[2][2];
  #pragma unroll
  for (int i=0;i<2;i++)
    #pragma unroll
    for (int j=0;j<2;j++) acc[i][j] = (f32x4){0.f,0.f,0.f,0.f};

  for (int k0 = 0; k0 < K; k0 += 32) {
    if (!TRA) {
      int k = tid & 31, m0 = tid >> 5;               // coalesced along k
      #pragma unroll
      for (int u = 0; u < 8; u++) {
        int m = m0 + u*8;
        float f = A[(long)(bm+m)*lda + k0 + k];
        unsigned short h = f2bs(f);
        As[0][m][k] = h;
        As[1][m][k] = f2bs(f - bs2f(h));
      }
    } else {
      int m = tid & 63, kk0 = tid >> 6;              // coalesced along m
      #pragma unroll
      for (int u = 0; u < 8; u++) {
        int k = kk0 + u*4;
        float f = A[(long)(k0+k)*lda + bm + m];
        unsigned short h = f2bs(f);
        As[0][m][k] = h;
        As[1][m][k] = f2bs(f - bs2f(h));
      }
    }
    if (TRB) {
      int k = tid & 31, n0 = tid >> 5;
      #pragma unroll
      for (int u = 0; u < 8; u++) {
        int n = n0 + u*8;
        float f = Bp[(long)(bn+n)*ldb + k0 + k];
        unsigned short h = f2bs(f);
        Bs[0][n][k] = h;
        Bs[1][n][k] = f2bs(f - bs2f(h));
      }
    } else {
      int n = tid & 63, kk0 = tid >> 6;
      #pragma unroll
      for (int u = 0; u < 8; u++) {
        int k = kk0 + u*4;
        float f = Bp[(long)(k0+k)*ldb + bn + n];
        unsigned short h = f2bs(f);
        Bs[0][n][k] = h;
        Bs[1][n][k] = f2bs(f - bs2f(h));
      }
    }
    __syncthreads();
    bfrag ah0 = *reinterpret_cast<const bfrag*>(&As[0][wr + fm][fk]);
    bfrag ah1 = *reinterpret_cast<const bfrag*>(&As[0][wr + 16 + fm][fk]);
    bfrag bh0 = *reinterpret_cast<const bfrag*>(&Bs[0][wc + fm][fk]);
    bfrag bh1 = *reinterpret_cast<const bfrag*>(&Bs[0][wc + 16 + fm][fk]);
    bfrag al0 = *reinterpret_cast<const bfrag*>(&As[1][wr + fm][fk]);
    bfrag al1 = *reinterpret_cast<const bfrag*>(&As[1][wr + 16 + fm][fk]);
    bfrag bl0 = *reinterpret_cast<const bfrag*>(&Bs[1][wc + fm][fk]);
    bfrag bl1 = *reinterpret_cast<const bfrag*>(&Bs[1][wc + 16 + fm][fk]);
    acc[0][0] = __builtin_amdgcn_mfma_f32_16x16x32_bf16(ah0, bh0, acc[0][0], 0,0,0);
    acc[0][1] = __builtin_amdgcn_mfma_f32_16x16x32_bf16(ah0, bh1, acc[0][1], 0,0,0);
    acc[1][0] = __builtin_amdgcn_mfma_f32_16x16x32_bf16(ah1, bh0, acc[1][0], 0,0,0);
    acc[1][1] = __builtin_amdgcn_mfma_f32_16x16x32_bf16(ah1, bh1, acc[1][1], 0,0,0);
    acc[0][0] = __builtin_amdgcn_mfma_f32_16x16x32_bf16(ah0, bl0, acc[0][0], 0,0,0);
    acc[0][1] = __builtin_amdgcn_mfma_f32_16x16x32_bf16(ah0, bl1, acc[0][1], 0,0,0);
    acc[1][0] = __builtin_amdgcn_mfma_f32_16x16x32_bf16(ah1, bl0, acc[1][0], 0,0,0);
    acc[1][1] = __builtin_amdgcn_mfma_f32_16x16x32_bf16(ah1, bl1, acc[1][1], 0,0,0);
    acc[0][0] = __builtin_amdgcn_mfma_f32_16x16x32_bf16(al0, bh0, acc[0][0], 0,0,0);
    acc[0][1] = __builtin_amdgcn_mfma_f32_16x16x32_bf16(al0, bh1, acc[0][1], 0,0,0);
    acc[1][0] = __builtin_amdgcn_mfma_f32_16x16x32_bf16(al1, bh0, acc[1][0], 0,0,0);
    acc[1][1] = __builtin_amdgcn_mfma_f32_16x16x32_bf16(al1, bh1, acc[1][1], 0,0,0);
    __syncthreads();
  }

  // C/D layout: col = lane&15, row = (lane>>4)*4 + reg
  #pragma unroll
  for (int i=0;i<2;i++) {
    #pragma unroll
    for (int j=0;j<2;j++) {
      #pragma unroll
      for (int r=0;r<4;r++) {
        int row = bm + wr + i*16 + (lane>>4)*4 + r;
        int col = bn + wc + j*16 + fm;
        float v = acc[i][j][r];
        if (EPI == EPI_SILU)          v = v / (1.f + __expf(-v));
        else if (EPI == EPI_SUB)      v = v - E[(long)row*lde + col];
        else if (EPI == EPI_LINCOMB)  v = a0*E[(long)row*lde + col] + a1*v;
        else if (EPI == EPI_MUL)      v = v * E[(long)row*lde + col];
        else if (EPI == EPI_ADD)      v = v + E[(long)row*lde + col];
        else if (EPI == EPI_SILU_MUL) v = (v / (1.f + __expf(-v))) * E[(long)row*lde + col];
        stf(&C[(long)row*ldc + col], v);
      }
    }
  }
}

// xn = x * nw * rsqrt(mean(x^2)+eps); one block per row
__global__ __launch_bounds__(256) void rmsnorm_in_k(const float* __restrict__ x,
    const float* __restrict__ w, float* __restrict__ xn)
{
  __shared__ float sbuf[4];
  long row = blockIdx.x;
  const float* xr = x + row*SD;
  int c0 = threadIdx.x, c1 = threadIdx.x + 256;
  float v0 = xr[c0], v1 = xr[c1];
  float ss = block_sum256(v0*v0 + v1*v1, sbuf);
  float r = rsqrtf(ss*(1.f/SD) + 1e-6f);
  xn[row*SD + c0] = v0*r*w[c0];
  xn[row*SD + c1] = v1*r*w[c1];
}

// dst_row = rms(silu(dwconv3(raw_row))) * nw ;  one block per (t, b)
__global__ __launch_bounds__(256) void conv_silu_rms_k(const float* __restrict__ raw,
    const float* __restrict__ cw, const float* __restrict__ cb, const float* __restrict__ nw,
    float* __restrict__ dst, long dstBatchStride, int dstRowOff)
{
  __shared__ float sbuf[4];
  int t = blockIdx.x, b = blockIdx.y;
  const float* base = raw + ((long)b*SS + t)*SD;
  float vals[2];
  #pragma unroll
  for (int u = 0; u < 2; u++) {
    int c = threadIdx.x + u*256;
    float w0 = cw[c*3+0], w1 = cw[c*3+1], w2 = cw[c*3+2];
    float acc = cb[c];
    if (t > 0)     acc += base[c - SD]*w0;
    acc += base[c]*w1;
    if (t < SS-1)  acc += base[c + SD]*w2;
    vals[u] = acc / (1.f + __expf(-acc));
  }
  float ss = block_sum256(vals[0]*vals[0] + vals[1]*vals[1], sbuf);
  float r = rsqrtf(ss*(1.f/SD) + 1e-6f);
  float* out = dst + (long)b*dstBatchStride + (long)(dstRowOff + t)*SD;
  out[threadIdx.x]       = vals[0]*r*nw[threadIdx.x];
  out[threadIdx.x + 256] = vals[1]*r*nw[threadIdx.x + 256];
}

// per-(b,chunk) column means of a [B*S, 512] buffer -> [B*NCH, 512]
__global__ __launch_bounds__(256) void chunk_means1_k(const float* __restrict__ src,
    float* __restrict__ dst)
{
  int cb = blockIdx.x;          // b*32 + chunk
  long rowbase = (long)cb*SCH*SD;
  #pragma unroll
  for (int u = 0; u < 2; u++) {
    int col = threadIdx.x + u*256;
    float s = 0.f;
    for (int r = 0; r < SCH; r++) s += src[rowbase + (long)r*SD + col];
    dst[(long)cb*SD + col] = s * (1.f/SCH);
  }
}

__global__ __launch_bounds__(256) void frob_partial_k(const float* __restrict__ X,
    float* __restrict__ part)
{
  __shared__ float sbuf[4];
  int b = blockIdx.y;
  const float* base = X + (long)b*DD + (long)blockIdx.x*8192;
  float s = 0.f;
  for (int i = threadIdx.x; i < 8192; i += 256) { float v = base[i]; s += v*v; }
  s = block_sum256(s, sbuf);
  if (threadIdx.x == 0) part[b*32 + blockIdx.x] = s;
}

__global__ __launch_bounds__(256) void ns_scale_k(float* __restrict__ X,
    const float* __restrict__ part)
{
  int b = blockIdx.y;
  float s = 0.f;
  for (int i = 0; i < 32; i++) s += part[b*32 + i];
  float scale = 1.f / (sqrtf(s) + 1e-7f);
  long base = (long)b*DD + (long)blockIdx.x*4096;
  for (int i = threadIdx.x; i < 4096; i += 256) X[base + i] *= scale;
}

// M[b,i,j] = M[b,i,j]*alphaM[b,chunk,j] - X[b,i,j]*etaM[b,chunk,j]
__global__ __launch_bounds__(256) void update_M_k(float* __restrict__ M,
    const float* __restrict__ X, const float* __restrict__ etaM,
    const float* __restrict__ alphaM, int chunk)
{
  long idx = (long)blockIdx.x*256 + threadIdx.x;   // 524288 total
  int b = (int)(idx >> 18);
  int col = (int)(idx & (SD-1));
  long mo = ((long)(b*32 + chunk) << 9) + col;
  float al = alphaM[mo], et = etaM[mo];
  M[idx] = M[idx]*al - X[idx]*et;
}

// atlas epilogue (in place): t = rms(a)*nw_out*gb; a = rms(t)*n1_w
__global__ __launch_bounds__(256) void atlas_final_norm_k(float* __restrict__ a,
    const float* __restrict__ gb, const float* __restrict__ nwout,
    const float* __restrict__ n1w)
{
  __shared__ float sbuf[4];
  long row = blockIdx.x;
  float* xr = a + row*SD;
  int c0 = threadIdx.x, c1 = threadIdx.x + 256;
  float v0 = xr[c0], v1 = xr[c1];
  float ss = block_sum256(v0*v0 + v1*v1, sbuf);
  float r = rsqrtf(ss*(1.f/SD) + 1e-6f);
  float t0 = v0*r*nwout[c0] * gb[row*SD+c0];
  float t1 = v1*r*nwout[c1] * gb[row*SD+c1];
  float ss2 = block_sum256(t0*t0 + t1*t1, sbuf);
  float r2 = rsqrtf(ss2*(1.f/SD) + 1e-6f);
  xr[c0] = t0*r2*n1w[c0];
  xr[c1] = t1*r2*n1w[c1];
}

// dst = rms(o)*w + dst  (in place on dst)
__global__ __launch_bounds__(256) void rms_add_k(const float* __restrict__ o,
    const float* __restrict__ w, float* __restrict__ dst)
{
  __shared__ float sbuf[4];
  long row = blockIdx.x;
  const float* xr = o + row*SD;
  int c0 = threadIdx.x, c1 = threadIdx.x + 256;
  float v0 = xr[c0], v1 = xr[c1];
  float ss = block_sum256(v0*v0 + v1*v1, sbuf);
  float r = rsqrtf(ss*(1.f/SD) + 1e-6f);
  dst[row*SD+c0] += v0*r*w[c0];
  dst[row*SD+c1] += v1*r*w[c1];
}

// sliding-window attention, one wave per (b, h, query); 4 waves/block
__global__ __launch_bounds__(256) void attn_swa_k(const float* __restrict__ Q,
    const float* __restrict__ K, const float* __restrict__ V, float* __restrict__ O)
{
  __shared__ float sc[4][SWIN];
  int wid = threadIdx.x >> 6, lane = threadIdx.x & 63;
  int w = blockIdx.x*4 + wid;           // [0, B*H*S)
  int b = w >> 14;                       // / (H*S)
  int rem = w & 16383;
  int h = rem >> 11;                     // / S
  int i = rem & (SS-1);
  const float* qp = Q + ((long)b*SS + i)*SD + h*64;
  float qv = qp[lane];
  int j0 = i - (SWIN-1); if (j0 < 0) j0 = 0;
  int cnt = i - j0 + 1;
  const float* Kb = K + (long)b*SS*SD + h*64;
  const float* Vb = V + (long)b*SS*SD + h*64;
  float mx = -1e30f;
  for (int jj = 0; jj < cnt; jj++) {
    float p = qv * Kb[(long)(j0+jj)*SD + lane];
    #pragma unroll
    for (int o2 = 32; o2 > 0; o2 >>= 1) p += __shfl_xor(p, o2);
    p *= 0.125f;                         // 1/sqrt(64)
    if (lane == 0) sc[wid][jj] = p;
    mx = fmaxf(mx, p);
  }
  __syncthreads();
  float sum = 0.f, oa = 0.f;
  for (int jj = 0; jj < cnt; jj++) {
    float p = __expf(sc[wid][jj] - mx);
    sum += p;
    oa += p * Vb[(long)(j0+jj)*SD + lane];
  }
  O[((long)b*SS + i)*SD + h*64 + lane] = oa / sum;
}

__global__ __launch_bounds__(256) void copy_f_k(float* __restrict__ dst, long dstride,
    const float* __restrict__ src, long sstride, long nper, int nb)
{
  long total = nper * nb;
  for (long i = (long)blockIdx.x*256 + threadIdx.x; i < total; i += (long)gridDim.x*256) {
    long b = i / nper, r = i - b*nper;
    dst[b*dstride + r] = src[b*sstride + r];
  }
}

extern "C" void kernel_launch(void* const* d_in, const int* in_sizes, int n_in,
                              void* d_out, int out_size, void* d_ws, size_t ws_size,
                              hipStream_t stream)
{
  (void)in_sizes; (void)n_in; (void)out_size; (void)ws_size;
  const float* x      = (const float*)d_in[0];
  const float* mem0   = (const float*)d_in[1];
  const float* buf_k  = (const float*)d_in[2];
  const float* buf_v  = (const float*)d_in[3];
  const float* nw_in  = (const float*)d_in[4];
  const float* nw_kq  = (const float*)d_in[5];
  const float* nw_out = (const float*)d_in[6];
  const float* wk_a   = (const float*)d_in[7];
  const float* wq_a   = (const float*)d_in[8];
  const float* wv_a   = (const float*)d_in[9];
  const float* wg     = (const float*)d_in[10];
  const float* wb     = (const float*)d_in[11];
  const float* ck_w   = (const float*)d_in[12];
  const float* ck_b   = (const float*)d_in[13];
  const float* cq_w   = (const float*)d_in[14];
  const float* cq_b   = (const float*)d_in[15];
  const float* s1_wq  = (const float*)d_in[16];
  const float* s1_wk  = (const float*)d_in[17];
  const float* s1_wv  = (const float*)d_in[18];
  const float* s1_wo  = (const float*)d_in[19];
  const float* s2_wq  = (const float*)d_in[20];
  const float* s2_wk  = (const float*)d_in[21];
  const float* s2_wv  = (const float*)d_in[22];
  const float* s2_wo  = (const float*)d_in[23];
  const float* n1_w   = (const float*)d_in[24];
  const float* n2_w   = (const float*)d_in[25];
  const float* m_w1   = (const float*)d_in[26];
  const float* m_w2   = (const float*)d_in[27];
  const float* m_w3   = (const float*)d_in[28];
  float* ob = (float*)d_out;   // output dtype = float32

  // ---- workspace carve: 15,728,704 floats = 60.0 MB ----
  float* p = (float*)d_ws;
  float* kp   = p; p += SB*KPBATCH;   // padded k [B,2176,512]; C: attn out; MLP: h1 head
  float* vp   = p; p += SB*KPBATCH;   // padded v; C: oproj1 out; MLP: h1
  float* qbuf = p; p += SB*BSD;       // atlas q; C: v1/v2; MLP: h1
  float* gb   = p; p += SB*BSD;       // gamma*bypass; C: k1/k2; MLP: h1 tail
  float* sc1  = p; p += SB*BSD;       // xn; C: q1/q2, y
  float* sc2  = p; p += SB*BSD;       // kraw/qraw; B: aout; C: memn->fused
  float* Mb   = p; p += SB*DD;        // (Mb..Am also = nsbuf for eta/alpha gemms)
  float* X0   = p; p += SB*DD;
  float* X1   = p; p += SB*DD;
  float* Am   = p; p += SB*DD;
  float* Tm   = p; p += SB*DD;
  float* err  = p; p += (long)SB*(SWIN+SCH)*SD;
  float* etaM = p; p += (long)SB*SNCH*SD;
  float* alphaM = p; p += (long)SB*SNCH*SD;
  float* partials = p; p += 64;
  float* nsbuf = Mb;                  // 4*DD floats, phase-A only
  float* aout = sc2;
  float* hbuf = kp;                   // MLP h1/h2: kp..gb span (8,650,752 >= 8,388,608)

  dim3 blk(256);

  // ================= Phase A =================
  rmsnorm_in_k<<<SB*SS, blk, 0, stream>>>(x, nw_in, sc1);

  // v = silu(xn @ wv_a.T) -> vp interior
  mgemm_k<false,true,EPI_SILU,float><<<dim3(32,8,2),blk,0,stream>>>(
      sc1, wv_a, vp + (long)SWIN*SD, nullptr, 0.f,0.f, SS, SD, SD,
      BSD, 0, KPBATCH, 0, SD, SD, SD, 0);

  // k path: proj -> sc2 ; conv+silu+rms -> kp interior
  mgemm_k<false,true,EPI_NONE,float><<<dim3(64,8,1),blk,0,stream>>>(
      sc1, wk_a, sc2, nullptr, 0.f,0.f, SB*SS, SD, SD, 0,0,0,0, SD,SD,SD,0);
  conv_silu_rms_k<<<dim3(SS,SB),blk,0,stream>>>(sc2, ck_w, ck_b, nw_kq, kp, KPBATCH, SWIN);

  // q path -> qbuf
  mgemm_k<false,true,EPI_NONE,float><<<dim3(64,8,1),blk,0,stream>>>(
      sc1, wq_a, sc2, nullptr, 0.f,0.f, SB*SS, SD, SD, 0,0,0,0, SD,SD,SD,0);
  conv_silu_rms_k<<<dim3(SS,SB),blk,0,stream>>>(sc2, cq_w, cq_b, nw_kq, qbuf, BSD, 0);

  // gamma = silu(xn @ wg[0:512].T) -> gb; then gb = silu(xn @ wb.T) * gb
  mgemm_k<false,true,EPI_SILU,float><<<dim3(64,8,1),blk,0,stream>>>(
      sc1, wg, gb, nullptr, 0.f,0.f, SB*SS, SD, SD, 0,0,0,0, SD,SD,SD,0);
  mgemm_k<false,true,EPI_SILU_MUL,float><<<dim3(64,8,1),blk,0,stream>>>(
      sc1, wb, gb, gb, 0.f,0.f, SB*SS, SD, SD, 0,0,0,0, SD,SD,SD,SD);

  // eta means: silu(xn @ wg[512:1024].T) -> nsbuf -> etaM
  mgemm_k<false,true,EPI_SILU,float><<<dim3(64,8,1),blk,0,stream>>>(
      sc1, wg + (long)SD*SD, nsbuf, nullptr, 0.f,0.f, SB*SS, SD, SD, 0,0,0,0, SD,SD,SD,0);
  chunk_means1_k<<<SB*SNCH, blk, 0, stream>>>(nsbuf, etaM);
  // alpha means
  mgemm_k<false,true,EPI_SILU,float><<<dim3(64,8,1),blk,0,stream>>>(
      sc1, wg + 2L*SD*SD, nsbuf, nullptr, 0.f,0.f, SB*SS, SD, SD, 0,0,0,0, SD,SD,SD,0);
  chunk_means1_k<<<SB*SNCH, blk, 0, stream>>>(nsbuf, alphaM);

  // heads of kp/vp; M init (AFTER nsbuf use — Mb aliases nsbuf)
  copy_f_k<<<256,blk,0,stream>>>(kp, KPBATCH, buf_k, (long)SWIN*SD, (long)SWIN*SD, SB);
  copy_f_k<<<256,blk,0,stream>>>(vp, KPBATCH, buf_v, (long)SWIN*SD, (long)SWIN*SD, SB);
  copy_f_k<<<256,blk,0,stream>>>(Mb, DD, mem0, DD, DD, SB);

  // ================= Phase B: sequential chunk scan =================
  for (int t = 0; t < SNCH; ++t) {
    const float* ck = kp + (long)t*SCH*SD;
    const float* cv = vp + (long)t*SCH*SD;
    // err = ctx_k @ M - ctx_v   [b,192,512]
    mgemm_k<false,false,EPI_SUB,float><<<dim3(3,8,2),blk,0,stream>>>(
        ck, Mb, err, cv, 0.f,0.f, SWIN+SCH, SD, SD,
        KPBATCH, DD, (long)(SWIN+SCH)*SD, KPBATCH, SD, SD, SD, SD);
    // grad = ctx_k^T @ err -> X0
    mgemm_k<true,false,EPI_NONE,float><<<dim3(8,8,2),blk,0,stream>>>(
        ck, err, X0, nullptr, 0.f,0.f, SD, SD, SWIN+SCH,
        KPBATCH, (long)(SWIN+SCH)*SD, DD, 0, SD, SD, SD, 0);
    // X0 /= (||G||_F + 1e-7)
    frob_partial_k<<<dim3(32,2),blk,0,stream>>>(X0, partials);
    ns_scale_k<<<dim3(64,2),blk,0,stream>>>(X0, partials);
    // 5 Newton-Schulz iterations
    float* Xc = X0; float* Xn = X1;
    for (int it = 0; it < 5; ++it) {
      mgemm_k<false,true,EPI_NONE,float><<<dim3(8,8,2),blk,0,stream>>>(
          Xc, Xc, Am, nullptr, 0.f,0.f, SD,SD,SD, DD,DD,DD,0, SD,SD,SD,0);
      mgemm_k<false,false,EPI_LINCOMB,float><<<dim3(8,8,2),blk,0,stream>>>(
          Am, Am, Tm, Am, -4.7750f, 2.0315f, SD,SD,SD, DD,DD,DD,DD, SD,SD,SD,SD);
      mgemm_k<false,false,EPI_LINCOMB,float><<<dim3(8,8,2),blk,0,stream>>>(
          Tm, Xc, Xn, Xc, 3.4445f, 1.0f, SD,SD,SD, DD,DD,DD,DD, SD,SD,SD,SD);
      float* tmp = Xc; Xc = Xn; Xn = tmp;
    }
    // M = M*alpha_mean - og*eta_mean
    update_M_k<<<2048,blk,0,stream>>>(Mb, Xc, etaM, alphaM, t);
    // out_chunk = cq @ M -> aout(=sc2)
    mgemm_k<false,false,EPI_NONE,float><<<dim3(1,8,2),blk,0,stream>>>(
        qbuf + (long)t*SCH*SD, Mb, aout + (long)t*SCH*SD, nullptr, 0.f,0.f,
        SCH, SD, SD, BSD, DD, BSD, 0, SD, SD, SD, 0);
  }

  // ================= Phase C =================
  // mem_normed in place into sc2
  atlas_final_norm_k<<<SB*SS,blk,0,stream>>>(sc2, gb, nw_out, n1_w);

  // side outputs now (frees kp/vp/Mb for reuse) — f32 copies into f32 d_out
  copy_f_k<<<256,blk,0,stream>>>(ob + (long)SB*SS*SD, DD, Mb, DD, DD, SB);
  copy_f_k<<<256,blk,0,stream>>>(ob + (long)SB*SS*SD + SB*DD, (long)SWIN*SD,
      kp + (long)SS*SD, KPBATCH, (long)SWIN*SD, SB);
  copy_f_k<<<256,blk,0,stream>>>(ob + (long)SB*SS*SD + SB*DD + (long)SB*SWIN*SD, (long)SWIN*SD,
      vp + (long)SS*SD, KPBATCH, (long)SWIN*SD, SB);

  // SWA 1 on x: q->sc1, k->gb, v->qbuf; attn->kp; oproj->vp; fused: sc2 += rms(vp)*n2
  mgemm_k<false,true,EPI_NONE,float><<<dim3(64,8,1),blk,0,stream>>>(
      x, s1_wq, sc1, nullptr,0.f,0.f, SB*SS, SD, SD, 0,0,0,0, SD,SD,SD,0);
  mgemm_k<false,true,EPI_NONE,float><<<dim3(64,8,1),blk,0,stream>>>(
      x, s1_wk, gb, nullptr,0.f,0.f, SB*SS, SD, SD, 0,0,0,0, SD,SD,SD,0);
  mgemm_k<false,true,EPI_NONE,float><<<dim3(64,8,1),blk,0,stream>>>(
      x, s1_wv, qbuf, nullptr,0.f,0.f, SB*SS, SD, SD, 0,0,0,0, SD,SD,SD,0);
  attn_swa_k<<<SB*SH*SS/4, blk, 0, stream>>>(sc1, gb, qbuf, kp);
  mgemm_k<false,true,EPI_NONE,float><<<dim3(64,8,1),blk,0,stream>>>(
      kp, s1_wo, vp, nullptr,0.f,0.f, SB*SS, SD, SD, 0,0,0,0, SD,SD,SD,0);
  rms_add_k<<<SB*SS,blk,0,stream>>>(vp, n2_w, sc2);   // sc2 = fused

  // SWA 2 on fused(sc2): q->sc1, k->gb, v->qbuf; attn->kp; y->sc1
  mgemm_k<false,true,EPI_NONE,float><<<dim3(64,8,1),blk,0,stream>>>(
      sc2, s2_wq, sc1, nullptr,0.f,0.f, SB*SS, SD, SD, 0,0,0,0, SD,SD,SD,0);
  mgemm_k<false,true,EPI_NONE,float><<<dim3(64,8,1),blk,0,stream>>>(
      sc2, s2_wk, gb, nullptr,0.f,0.f, SB*SS, SD, SD, 0,0,0,0, SD,SD,SD,0);
  mgemm_k<false,true,EPI_NONE,float><<<dim3(64,8,1),blk,0,stream>>>(
      sc2, s2_wv, qbuf, nullptr,0.f,0.f, SB*SS, SD, SD, 0,0,0,0, SD,SD,SD,0);
  attn_swa_k<<<SB*SH*SS/4, blk, 0, stream>>>(sc1, gb, qbuf, kp);
  mgemm_k<false,true,EPI_NONE,float><<<dim3(64,8,1),blk,0,stream>>>(
      kp, s2_wo, sc1, nullptr,0.f,0.f, SB*SS, SD, SD, 0,0,0,0, SD,SD,SD,0); // y=sc1

  // MLP: h1 = silu(y@w1.T) -> hbuf; h2 = (y@w2.T)*h1 in place; out = h2@w3.T + fused(sc2)
  mgemm_k<false,true,EPI_SILU,float><<<dim3(64,32,1),blk,0,stream>>>(
      sc1, m_w1, hbuf, nullptr,0.f,0.f, SB*SS, SFF, SD, 0,0,0,0, SD,SD,SFF,0);
  mgemm_k<false,true,EPI_MUL,float><<<dim3(64,32,1),blk,0,stream>>>(
      sc1, m_w2, hbuf, hbuf, 0.f,0.f, SB*SS, SFF, SD, 0,0,0,0, SD,SD,SFF,SFF);
  mgemm_k<false,true,EPI_ADD,float><<<dim3(64,8,1),blk,0,stream>>>(
      hbuf, m_w3, ob, sc2, 0.f,0.f, SB*SS, SD, SFF, 0,0,0,0, SFF,SFF,SD,SD);
}

// Round 7
// 9963.559 us; speedup vs baseline: 2.7490x; 1.2345x over previous
//
#include <hip/hip_runtime.h>
#include <hip/hip_bf16.h>

typedef __hip_bfloat16 bf16;
typedef __attribute__((ext_vector_type(8))) short bfrag;            // 8 bf16 = 4 VGPRs
typedef __attribute__((ext_vector_type(8))) unsigned short u16x8;   // 16B copy unit
typedef __attribute__((ext_vector_type(4))) float f32x4;

#define SB 2
#define SS 2048
#define SD 512
#define SH 8
#define SWIN 128
#define SCH 64
#define SNCH 32
#define SFF 2048
#define KPROWS 2176              // WIN + S
#define KPBATCH 1114112L         // KPROWS*SD
#define BSD 1048576L             // SS*SD
#define DD 262144L               // SD*SD
#define ERRN 98304L              // 192*SD

__device__ __forceinline__ void stf(float* p, float v){ *p = v; }
__device__ __forceinline__ void stf(bf16* p, float v){ *p = __float2bfloat16(v); }

// f32 -> bf16 bits, round-to-nearest-even (finite inputs)
__device__ __forceinline__ unsigned short f2bs(float f){
  union { float f; unsigned int u; } v; v.f = f;
  unsigned int r = v.u + 0x7FFFu + ((v.u >> 16) & 1u);
  return (unsigned short)(r >> 16);
}
__device__ __forceinline__ float bs2f(unsigned short h){
  union { unsigned int u; float f; } v; v.u = ((unsigned int)h) << 16;
  return v.f;
}

__device__ __forceinline__ float block_sum256(float v, float* sbuf){
  #pragma unroll
  for (int o = 32; o > 0; o >>= 1) v += __shfl_xor(v, o);
  int wid = threadIdx.x >> 6;
  if ((threadIdx.x & 63) == 0) sbuf[wid] = v;
  __syncthreads();
  float r = sbuf[0] + sbuf[1] + sbuf[2] + sbuf[3];
  __syncthreads();
  return r;
}

enum { EPI_NONE=0, EPI_SILU=1, EPI_SUB=2, EPI_LINCOMB=3, EPI_MUL=4, EPI_ADD=5, EPI_SILU_MUL=6 };

// ===================== split-pair MFMA GEMM (scan) =====================
// Inputs pre-split into bf16 hi/lo planes (plane stride pA/pB elements).
// C = op(A) @ op(B) via 3-term Dekker (hi*hi + hi*lo + lo*hi), f32 accum.
// TRA: A given [K,M]. TRB: B given [N,K]. M%64==N%64==K%32==0.
template<bool TRA, bool TRB, int EPI, bool EPAIR, bool OSPLIT, bool OF32>
__global__ __launch_bounds__(256)
void sgemm_k(const unsigned short* __restrict__ Ahl, const unsigned short* __restrict__ Bhl,
             float* __restrict__ Cf, unsigned short* __restrict__ Chl,
             const float* __restrict__ Ef, const unsigned short* __restrict__ Ehl,
             float a0, float a1, int M, int N, int K,
             long sA, long pA, long sB, long pB,
             long sCf, long sChl, long pC, long sE, long pE,
             int lda, int ldb, int ldc, int lde)
{
  __shared__ __align__(16) unsigned short As[2][64][40];
  __shared__ __align__(16) unsigned short Bs[2][64][40];
  const int bz = blockIdx.z;
  const unsigned short* A = Ahl + (long)bz*sA;
  const unsigned short* B = Bhl + (long)bz*sB;
  const int bm = blockIdx.x*64, bn = blockIdx.y*64;
  const int tid = threadIdx.x;
  const int lane = tid & 63, wid = tid >> 6;
  const int wr = (wid >> 1)*32, wc = (wid & 1)*32;
  const int fm = lane & 15, fk = (lane >> 4)*8;

  f32x4 acc[2][2];
  #pragma unroll
  for (int i=0;i<2;i++)
    #pragma unroll
    for (int j=0;j<2;j++) acc[i][j] = (f32x4){0.f,0.f,0.f,0.f};

  for (int k0 = 0; k0 < K; k0 += 32) {
    if (!TRA) {
      int row = tid >> 2, cb = (tid & 3) << 3;
      const unsigned short* a0 = A + (long)(bm+row)*lda + k0 + cb;
      *reinterpret_cast<u16x8*>(&As[0][row][cb]) = *reinterpret_cast<const u16x8*>(a0);
      *reinterpret_cast<u16x8*>(&As[1][row][cb]) = *reinterpret_cast<const u16x8*>(a0 + pA);
    } else {
      int k = tid >> 3, m0 = (tid & 7) << 3;
      const unsigned short* a0 = A + (long)(k0+k)*lda + bm + m0;
      u16x8 vh = *reinterpret_cast<const u16x8*>(a0);
      u16x8 vl = *reinterpret_cast<const u16x8*>(a0 + pA);
      #pragma unroll
      for (int j=0;j<8;j++){ As[0][m0+j][k]=vh[j]; As[1][m0+j][k]=vl[j]; }
    }
    if (TRB) {
      int row = tid >> 2, cb = (tid & 3) << 3;
      const unsigned short* b0 = B + (long)(bn+row)*ldb + k0 + cb;
      *reinterpret_cast<u16x8*>(&Bs[0][row][cb]) = *reinterpret_cast<const u16x8*>(b0);
      *reinterpret_cast<u16x8*>(&Bs[1][row][cb]) = *reinterpret_cast<const u16x8*>(b0 + pB);
    } else {
      int k = tid >> 3, n0 = (tid & 7) << 3;
      const unsigned short* b0 = B + (long)(k0+k)*ldb + bn + n0;
      u16x8 vh = *reinterpret_cast<const u16x8*>(b0);
      u16x8 vl = *reinterpret_cast<const u16x8*>(b0 + pB);
      #pragma unroll
      for (int j=0;j<8;j++){ Bs[0][n0+j][k]=vh[j]; Bs[1][n0+j][k]=vl[j]; }
    }
    __syncthreads();
    bfrag ah0 = *reinterpret_cast<const bfrag*>(&As[0][wr + fm][fk]);
    bfrag ah1 = *reinterpret_cast<const bfrag*>(&As[0][wr + 16 + fm][fk]);
    bfrag bh0 = *reinterpret_cast<const bfrag*>(&Bs[0][wc + fm][fk]);
    bfrag bh1 = *reinterpret_cast<const bfrag*>(&Bs[0][wc + 16 + fm][fk]);
    bfrag al0 = *reinterpret_cast<const bfrag*>(&As[1][wr + fm][fk]);
    bfrag al1 = *reinterpret_cast<const bfrag*>(&As[1][wr + 16 + fm][fk]);
    bfrag bl0 = *reinterpret_cast<const bfrag*>(&Bs[1][wc + fm][fk]);
    bfrag bl1 = *reinterpret_cast<const bfrag*>(&Bs[1][wc + 16 + fm][fk]);
    acc[0][0] = __builtin_amdgcn_mfma_f32_16x16x32_bf16(ah0, bh0, acc[0][0], 0,0,0);
    acc[0][1] = __builtin_amdgcn_mfma_f32_16x16x32_bf16(ah0, bh1, acc[0][1], 0,0,0);
    acc[1][0] = __builtin_amdgcn_mfma_f32_16x16x32_bf16(ah1, bh0, acc[1][0], 0,0,0);
    acc[1][1] = __builtin_amdgcn_mfma_f32_16x16x32_bf16(ah1, bh1, acc[1][1], 0,0,0);
    acc[0][0] = __builtin_amdgcn_mfma_f32_16x16x32_bf16(ah0, bl0, acc[0][0], 0,0,0);
    acc[0][1] = __builtin_amdgcn_mfma_f32_16x16x32_bf16(ah0, bl1, acc[0][1], 0,0,0);
    acc[1][0] = __builtin_amdgcn_mfma_f32_16x16x32_bf16(ah1, bl0, acc[1][0], 0,0,0);
    acc[1][1] = __builtin_amdgcn_mfma_f32_16x16x32_bf16(ah1, bl1, acc[1][1], 0,0,0);
    acc[0][0] = __builtin_amdgcn_mfma_f32_16x16x32_bf16(al0, bh0, acc[0][0], 0,0,0);
    acc[0][1] = __builtin_amdgcn_mfma_f32_16x16x32_bf16(al0, bh1, acc[0][1], 0,0,0);
    acc[1][0] = __builtin_amdgcn_mfma_f32_16x16x32_bf16(al1, bh0, acc[1][0], 0,0,0);
    acc[1][1] = __builtin_amdgcn_mfma_f32_16x16x32_bf16(al1, bh1, acc[1][1], 0,0,0);
    __syncthreads();
  }

  #pragma unroll
  for (int i=0;i<2;i++) {
    #pragma unroll
    for (int j=0;j<2;j++) {
      #pragma unroll
      for (int r=0;r<4;r++) {
        int row = bm + wr + i*16 + (lane>>4)*4 + r;
        int col = bn + wc + j*16 + fm;
        float v = acc[i][j][r];
        if (EPI == EPI_SUB || EPI == EPI_LINCOMB) {
          long eidx = (long)bz*sE + (long)row*lde + col;
          float e = EPAIR ? (bs2f(Ehl[eidx]) + bs2f(Ehl[eidx + pE])) : Ef[eidx];
          if (EPI == EPI_SUB) v = v - e;
          else                v = a0*e + a1*v;
        }
        if (OF32) Cf[(long)bz*sCf + (long)row*ldc + col] = v;
        if (OSPLIT) {
          long cidx = (long)bz*sChl + (long)row*ldc + col;
          unsigned short h = f2bs(v);
          Chl[cidx]      = h;
          Chl[cidx + pC] = f2bs(v - bs2f(h));
        }
      }
    }
  }
}

// ===================== f32-input MFMA GEMM (phase A/C, converts in-kernel) =====================
template<bool TRA, bool TRB, int EPI, typename TO>
__global__ __launch_bounds__(256)
void mgemm_k(const float* __restrict__ Ag, const float* __restrict__ Bg, TO* __restrict__ Cg,
             const float* __restrict__ Eg, float a0, float a1,
             int M, int N, int K,
             long sA, long sB, long sC, long sE,
             int lda, int ldb, int ldc, int lde)
{
  __shared__ __align__(16) unsigned short As[2][64][40];
  __shared__ __align__(16) unsigned short Bs[2][64][40];
  const int bz = blockIdx.z;
  const float* A = Ag + (long)bz*sA;
  const float* Bp = Bg + (long)bz*sB;
  TO* C = Cg + (long)bz*sC;
  const float* E = Eg ? (Eg + (long)bz*sE) : nullptr;
  const int bm = blockIdx.x*64, bn = blockIdx.y*64;
  const int tid = threadIdx.x;
  const int lane = tid & 63, wid = tid >> 6;
  const int wr = (wid >> 1)*32, wc = (wid & 1)*32;
  const int fm = lane & 15, fk = (lane >> 4)*8;

  f32x4 acc[2][2];
  #pragma unroll
  for (int i=0;i<2;i++)
    #pragma unroll
    for (int j=0;j<2;j++) acc[i][j] = (f32x4){0.f,0.f,0.f,0.f};

  for (int k0 = 0; k0 < K; k0 += 32) {
    if (!TRA) {
      int k = tid & 31, m0 = tid >> 5;
      #pragma unroll
      for (int u = 0; u < 8; u++) {
        int m = m0 + u*8;
        float f = A[(long)(bm+m)*lda + k0 + k];
        unsigned short h = f2bs(f);
        As[0][m][k] = h;
        As[1][m][k] = f2bs(f - bs2f(h));
      }
    } else {
      int m = tid & 63, kk0 = tid >> 6;
      #pragma unroll
      for (int u = 0; u < 8; u++) {
        int k = kk0 + u*4;
        float f = A[(long)(k0+k)*lda + bm + m];
        unsigned short h = f2bs(f);
        As[0][m][k] = h;
        As[1][m][k] = f2bs(f - bs2f(h));
      }
    }
    if (TRB) {
      int k = tid & 31, n0 = tid >> 5;
      #pragma unroll
      for (int u = 0; u < 8; u++) {
        int n = n0 + u*8;
        float f = Bp[(long)(bn+n)*ldb + k0 + k];
        unsigned short h = f2bs(f);
        Bs[0][n][k] = h;
        Bs[1][n][k] = f2bs(f - bs2f(h));
      }
    } else {
      int n = tid & 63, kk0 = tid >> 6;
      #pragma unroll
      for (int u = 0; u < 8; u++) {
        int k = kk0 + u*4;
        float f = Bp[(long)(k0+k)*ldb + bn + n];
        unsigned short h = f2bs(f);
        Bs[0][n][k] = h;
        Bs[1][n][k] = f2bs(f - bs2f(h));
      }
    }
    __syncthreads();
    bfrag ah0 = *reinterpret_cast<const bfrag*>(&As[0][wr + fm][fk]);
    bfrag ah1 = *reinterpret_cast<const bfrag*>(&As[0][wr + 16 + fm][fk]);
    bfrag bh0 = *reinterpret_cast<const bfrag*>(&Bs[0][wc + fm][fk]);
    bfrag bh1 = *reinterpret_cast<const bfrag*>(&Bs[0][wc + 16 + fm][fk]);
    bfrag al0 = *reinterpret_cast<const bfrag*>(&As[1][wr + fm][fk]);
    bfrag al1 = *reinterpret_cast<const bfrag*>(&As[1][wr + 16 + fm][fk]);
    bfrag bl0 = *reinterpret_cast<const bfrag*>(&Bs[1][wc + fm][fk]);
    bfrag bl1 = *reinterpret_cast<const bfrag*>(&Bs[1][wc + 16 + fm][fk]);
    acc[0][0] = __builtin_amdgcn_mfma_f32_16x16x32_bf16(ah0, bh0, acc[0][0], 0,0,0);
    acc[0][1] = __builtin_amdgcn_mfma_f32_16x16x32_bf16(ah0, bh1, acc[0][1], 0,0,0);
    acc[1][0] = __builtin_amdgcn_mfma_f32_16x16x32_bf16(ah1, bh0, acc[1][0], 0,0,0);
    acc[1][1] = __builtin_amdgcn_mfma_f32_16x16x32_bf16(ah1, bh1, acc[1][1], 0,0,0);
    acc[0][0] = __builtin_amdgcn_mfma_f32_16x16x32_bf16(ah0, bl0, acc[0][0], 0,0,0);
    acc[0][1] = __builtin_amdgcn_mfma_f32_16x16x32_bf16(ah0, bl1, acc[0][1], 0,0,0);
    acc[1][0] = __builtin_amdgcn_mfma_f32_16x16x32_bf16(ah1, bl0, acc[1][0], 0,0,0);
    acc[1][1] = __builtin_amdgcn_mfma_f32_16x16x32_bf16(ah1, bl1, acc[1][1], 0,0,0);
    acc[0][0] = __builtin_amdgcn_mfma_f32_16x16x32_bf16(al0, bh0, acc[0][0], 0,0,0);
    acc[0][1] = __builtin_amdgcn_mfma_f32_16x16x32_bf16(al0, bh1, acc[0][1], 0,0,0);
    acc[1][0] = __builtin_amdgcn_mfma_f32_16x16x32_bf16(al1, bh0, acc[1][0], 0,0,0);
    acc[1][1] = __builtin_amdgcn_mfma_f32_16x16x32_bf16(al1, bh1, acc[1][1], 0,0,0);
    __syncthreads();
  }

  #pragma unroll
  for (int i=0;i<2;i++) {
    #pragma unroll
    for (int j=0;j<2;j++) {
      #pragma unroll
      for (int r=0;r<4;r++) {
        int row = bm + wr + i*16 + (lane>>4)*4 + r;
        int col = bn + wc + j*16 + fm;
        float v = acc[i][j][r];
        if (EPI == EPI_SILU)          v = v / (1.f + __expf(-v));
        else if (EPI == EPI_SUB)      v = v - E[(long)row*lde + col];
        else if (EPI == EPI_LINCOMB)  v = a0*E[(long)row*lde + col] + a1*v;
        else if (EPI == EPI_MUL)      v = v * E[(long)row*lde + col];
        else if (EPI == EPI_ADD)      v = v + E[(long)row*lde + col];
        else if (EPI == EPI_SILU_MUL) v = (v / (1.f + __expf(-v))) * E[(long)row*lde + col];
        stf(&C[(long)row*ldc + col], v);
      }
    }
  }
}

// xn = x * nw * rsqrt(mean(x^2)+eps); one block per row
__global__ __launch_bounds__(256) void rmsnorm_in_k(const float* __restrict__ x,
    const float* __restrict__ w, float* __restrict__ xn)
{
  __shared__ float sbuf[4];
  long row = blockIdx.x;
  const float* xr = x + row*SD;
  int c0 = threadIdx.x, c1 = threadIdx.x + 256;
  float v0 = xr[c0], v1 = xr[c1];
  float ss = block_sum256(v0*v0 + v1*v1, sbuf);
  float r = rsqrtf(ss*(1.f/SD) + 1e-6f);
  xn[row*SD + c0] = v0*r*w[c0];
  xn[row*SD + c1] = v1*r*w[c1];
}

// dst_row = rms(silu(dwconv3(raw_row))) * nw ;  one block per (t, b)
__global__ __launch_bounds__(256) void conv_silu_rms_k(const float* __restrict__ raw,
    const float* __restrict__ cw, const float* __restrict__ cb, const float* __restrict__ nw,
    float* __restrict__ dst, long dstBatchStride, int dstRowOff)
{
  __shared__ float sbuf[4];
  int t = blockIdx.x, b = blockIdx.y;
  const float* base = raw + ((long)b*SS + t)*SD;
  float vals[2];
  #pragma unroll
  for (int u = 0; u < 2; u++) {
    int c = threadIdx.x + u*256;
    float w0 = cw[c*3+0], w1 = cw[c*3+1], w2 = cw[c*3+2];
    float acc = cb[c];
    if (t > 0)     acc += base[c - SD]*w0;
    acc += base[c]*w1;
    if (t < SS-1)  acc += base[c + SD]*w2;
    vals[u] = acc / (1.f + __expf(-acc));
  }
  float ss = block_sum256(vals[0]*vals[0] + vals[1]*vals[1], sbuf);
  float r = rsqrtf(ss*(1.f/SD) + 1e-6f);
  float* out = dst + (long)b*dstBatchStride + (long)(dstRowOff + t)*SD;
  out[threadIdx.x]       = vals[0]*r*nw[threadIdx.x];
  out[threadIdx.x + 256] = vals[1]*r*nw[threadIdx.x + 256];
}

// per-(b,chunk) column means of a [B*S, 512] buffer -> [B*NCH, 512]
__global__ __launch_bounds__(256) void chunk_means1_k(const float* __restrict__ src,
    float* __restrict__ dst)
{
  int cb = blockIdx.x;
  long rowbase = (long)cb*SCH*SD;
  #pragma unroll
  for (int u = 0; u < 2; u++) {
    int col = threadIdx.x + u*256;
    float s = 0.f;
    for (int r = 0; r < SCH; r++) s += src[rowbase + (long)r*SD + col];
    dst[(long)cb*SD + col] = s * (1.f/SCH);
  }
}

__global__ __launch_bounds__(256) void frob_partial_k(const float* __restrict__ X,
    float* __restrict__ part)
{
  __shared__ float sbuf[4];
  int b = blockIdx.y;
  const float* base = X + (long)b*DD + (long)blockIdx.x*8192;
  float s = 0.f;
  for (int i = threadIdx.x; i < 8192; i += 256) { float v = base[i]; s += v*v; }
  s = block_sum256(s, sbuf);
  if (threadIdx.x == 0) part[b*32 + blockIdx.x] = s;
}

// X0 *= 1/(||G||_F+1e-7), write split pair -> Xhl
__global__ __launch_bounds__(256) void ns_scale_split_k(const float* __restrict__ X,
    const float* __restrict__ part, unsigned short* __restrict__ Xhl)
{
  int b = blockIdx.y;
  float s = 0.f;
  for (int i = 0; i < 32; i++) s += part[b*32 + i];
  float scale = 1.f / (sqrtf(s) + 1e-7f);
  long base  = (long)b*DD + (long)blockIdx.x*4096;
  long obase = (long)b*2*DD + (long)blockIdx.x*4096;
  for (int i = threadIdx.x; i < 4096; i += 256) {
    float f = X[base + i] * scale;
    unsigned short h = f2bs(f);
    Xhl[obase + i]      = h;
    Xhl[obase + DD + i] = f2bs(f - bs2f(h));
  }
}

// M = M*alpha - X*eta on split pairs
__global__ __launch_bounds__(256) void update_Mp_k(unsigned short* __restrict__ Mhl,
    const unsigned short* __restrict__ Xhl, const float* __restrict__ etaM,
    const float* __restrict__ alphaM, int chunk)
{
  long idx = (long)blockIdx.x*256 + threadIdx.x;   // 524288 total = B*DD
  int b = (int)(idx >> 18);
  long r = idx & (DD-1);
  int col = (int)(idx & (SD-1));
  long mo = ((long)(b*32 + chunk) << 9) + col;
  long pb = (long)b*2*DD + r;
  float m  = bs2f(Mhl[pb]) + bs2f(Mhl[pb + DD]);
  float xv = bs2f(Xhl[pb]) + bs2f(Xhl[pb + DD]);
  float v = m*alphaM[mo] - xv*etaM[mo];
  unsigned short h = f2bs(v);
  Mhl[pb]      = h;
  Mhl[pb + DD] = f2bs(v - bs2f(h));
}

// atlas epilogue (in place): t = rms(a)*nw_out*gb; a = rms(t)*n1_w
__global__ __launch_bounds__(256) void atlas_final_norm_k(float* __restrict__ a,
    const float* __restrict__ gb, const float* __restrict__ nwout,
    const float* __restrict__ n1w)
{
  __shared__ float sbuf[4];
  long row = blockIdx.x;
  float* xr = a + row*SD;
  int c0 = threadIdx.x, c1 = threadIdx.x + 256;
  float v0 = xr[c0], v1 = xr[c1];
  float ss = block_sum256(v0*v0 + v1*v1, sbuf);
  float r = rsqrtf(ss*(1.f/SD) + 1e-6f);
  float t0 = v0*r*nwout[c0] * gb[row*SD+c0];
  float t1 = v1*r*nwout[c1] * gb[row*SD+c1];
  float ss2 = block_sum256(t0*t0 + t1*t1, sbuf);
  float r2 = rsqrtf(ss2*(1.f/SD) + 1e-6f);
  xr[c0] = t0*r2*n1w[c0];
  xr[c1] = t1*r2*n1w[c1];
}

// dst = rms(o)*w + dst  (in place on dst)
__global__ __launch_bounds__(256) void rms_add_k(const float* __restrict__ o,
    const float* __restrict__ w, float* __restrict__ dst)
{
  __shared__ float sbuf[4];
  long row = blockIdx.x;
  const float* xr = o + row*SD;
  int c0 = threadIdx.x, c1 = threadIdx.x + 256;
  float v0 = xr[c0], v1 = xr[c1];
  float ss = block_sum256(v0*v0 + v1*v1, sbuf);
  float r = rsqrtf(ss*(1.f/SD) + 1e-6f);
  dst[row*SD+c0] += v0*r*w[c0];
  dst[row*SD+c1] += v1*r*w[c1];
}

// sliding-window attention, one wave per (b, h, query); 4 waves/block
__global__ __launch_bounds__(256) void attn_swa_k(const float* __restrict__ Q,
    const float* __restrict__ K, const float* __restrict__ V, float* __restrict__ O)
{
  __shared__ float sc[4][SWIN];
  int wid = threadIdx.x >> 6, lane = threadIdx.x & 63;
  int w = blockIdx.x*4 + wid;
  int b = w >> 14;
  int rem = w & 16383;
  int h = rem >> 11;
  int i = rem & (SS-1);
  const float* qp = Q + ((long)b*SS + i)*SD + h*64;
  float qv = qp[lane];
  int j0 = i - (SWIN-1); if (j0 < 0) j0 = 0;
  int cnt = i - j0 + 1;
  const float* Kb = K + (long)b*SS*SD + h*64;
  const float* Vb = V + (long)b*SS*SD + h*64;
  float mx = -1e30f;
  for (int jj = 0; jj < cnt; jj++) {
    float p = qv * Kb[(long)(j0+jj)*SD + lane];
    #pragma unroll
    for (int o2 = 32; o2 > 0; o2 >>= 1) p += __shfl_xor(p, o2);
    p *= 0.125f;
    if (lane == 0) sc[wid][jj] = p;
    mx = fmaxf(mx, p);
  }
  __syncthreads();
  float sum = 0.f, oa = 0.f;
  for (int jj = 0; jj < cnt; jj++) {
    float p = __expf(sc[wid][jj] - mx);
    sum += p;
    oa += p * Vb[(long)(j0+jj)*SD + lane];
  }
  O[((long)b*SS + i)*SD + h*64 + lane] = oa / sum;
}

__global__ __launch_bounds__(256) void copy_f_k(float* __restrict__ dst, long dstride,
    const float* __restrict__ src, long sstride, long nper, int nb)
{
  long total = nper * nb;
  for (long i = (long)blockIdx.x*256 + threadIdx.x; i < total; i += (long)gridDim.x*256) {
    long b = i / nper, r = i - b*nper;
    dst[b*dstride + r] = src[b*sstride + r];
  }
}

// f32 -> hi/lo bf16 planes
__global__ __launch_bounds__(256) void split_k(unsigned short* __restrict__ dst,
    long dBatch, long dPlane, const float* __restrict__ src, long sBatch,
    long nper, int nb)
{
  long total = nper * nb;
  for (long i = (long)blockIdx.x*256 + threadIdx.x; i < total; i += (long)gridDim.x*256) {
    long b = i / nper, r = i - b*nper;
    float f = src[b*sBatch + r];
    unsigned short h = f2bs(f);
    dst[b*dBatch + r]          = h;
    dst[b*dBatch + dPlane + r] = f2bs(f - bs2f(h));
  }
}

// hi/lo planes -> f32
__global__ __launch_bounds__(256) void merge_k(float* __restrict__ dst, long dBatch,
    const unsigned short* __restrict__ src, long sBatch, long sPlane, long nper, int nb)
{
  long total = nper * nb;
  for (long i = (long)blockIdx.x*256 + threadIdx.x; i < total; i += (long)gridDim.x*256) {
    long b = i / nper, r = i - b*nper;
    dst[b*dBatch + r] = bs2f(src[b*sBatch + r]) + bs2f(src[b*sBatch + sPlane + r]);
  }
}

extern "C" void kernel_launch(void* const* d_in, const int* in_sizes, int n_in,
                              void* d_out, int out_size, void* d_ws, size_t ws_size,
                              hipStream_t stream)
{
  (void)in_sizes; (void)n_in; (void)out_size; (void)ws_size;
  const float* x      = (const float*)d_in[0];
  const float* mem0   = (const float*)d_in[1];
  const float* buf_k  = (const float*)d_in[2];
  const float* buf_v  = (const float*)d_in[3];
  const float* nw_in  = (const float*)d_in[4];
  const float* nw_kq  = (const float*)d_in[5];
  const float* nw_out = (const float*)d_in[6];
  const float* wk_a   = (const float*)d_in[7];
  const float* wq_a   = (const float*)d_in[8];
  const float* wv_a   = (const float*)d_in[9];
  const float* wg     = (const float*)d_in[10];
  const float* wb     = (const float*)d_in[11];
  const float* ck_w   = (const float*)d_in[12];
  const float* ck_b   = (const float*)d_in[13];
  const float* cq_w   = (const float*)d_in[14];
  const float* cq_b   = (const float*)d_in[15];
  const float* s1_wq  = (const float*)d_in[16];
  const float* s1_wk  = (const float*)d_in[17];
  const float* s1_wv  = (const float*)d_in[18];
  const float* s1_wo  = (const float*)d_in[19];
  const float* s2_wq  = (const float*)d_in[20];
  const float* s2_wk  = (const float*)d_in[21];
  const float* s2_wv  = (const float*)d_in[22];
  const float* s2_wo  = (const float*)d_in[23];
  const float* n1_w   = (const float*)d_in[24];
  const float* n2_w   = (const float*)d_in[25];
  const float* m_w1   = (const float*)d_in[26];
  const float* m_w2   = (const float*)d_in[27];
  const float* m_w3   = (const float*)d_in[28];
  float* ob = (float*)d_out;

  // ---- workspace carve: f32 section (~56MB) + u16 split arena (~55MB) ----
  float* p = (float*)d_ws;
  float* kp   = p; p += SB*KPBATCH;   // padded k f32; C: attn out; MLP: h1 head
  float* vp   = p; p += SB*KPBATCH;   // padded v f32; C: oproj1 out
  float* qbuf = p; p += SB*BSD;       // atlas q f32; C: v1/v2
  float* gb   = p; p += SB*BSD;       // gamma*bypass; C: k1/k2; MLP: h1 tail
  float* sc1  = p; p += SB*BSD;       // xn; C: q1/q2, y
  float* sc2  = p; p += SB*BSD;       // kraw/qraw; B: aout; C: memn->fused
  float* Mb   = p; p += SB*DD;        // mem0 f32 (split source)
  float* X0   = p; p += SB*DD;        // grad f32 (frob input)
  float* etaM = p; p += (long)SB*SNCH*SD;
  float* alphaM = p; p += (long)SB*SNCH*SD;
  float* partials = p; p += 64;
  unsigned short* us = (unsigned short*)p;
  unsigned short* khl = us; us += SB*2*KPBATCH;
  unsigned short* vhl = us; us += SB*2*KPBATCH;
  unsigned short* qhl = us; us += SB*2*BSD;
  unsigned short* Mhl = us; us += SB*2*DD;
  unsigned short* Xhl = us; us += SB*2*DD;
  unsigned short* Yhl = us; us += SB*2*DD;
  unsigned short* Ahl = us; us += SB*2*DD;
  unsigned short* Thl = us; us += SB*2*DD;
  unsigned short* errhl = us; us += SB*2*ERRN;
  float* nsbuf = (float*)khl;         // phase-A scratch (2M f32, before splits)
  float* aout = sc2;
  float* hbuf = kp;                   // MLP h1/h2: kp..gb span

  dim3 blk(256);

  // ================= Phase A =================
  rmsnorm_in_k<<<SB*SS, blk, 0, stream>>>(x, nw_in, sc1);

  mgemm_k<false,true,EPI_SILU,float><<<dim3(32,8,2),blk,0,stream>>>(
      sc1, wv_a, vp + (long)SWIN*SD, nullptr, 0.f,0.f, SS, SD, SD,
      BSD, 0, KPBATCH, 0, SD, SD, SD, 0);

  mgemm_k<false,true,EPI_NONE,float><<<dim3(64,8,1),blk,0,stream>>>(
      sc1, wk_a, sc2, nullptr, 0.f,0.f, SB*SS, SD, SD, 0,0,0,0, SD,SD,SD,0);
  conv_silu_rms_k<<<dim3(SS,SB),blk,0,stream>>>(sc2, ck_w, ck_b, nw_kq, kp, KPBATCH, SWIN);

  mgemm_k<false,true,EPI_NONE,float><<<dim3(64,8,1),blk,0,stream>>>(
      sc1, wq_a, sc2, nullptr, 0.f,0.f, SB*SS, SD, SD, 0,0,0,0, SD,SD,SD,0);
  conv_silu_rms_k<<<dim3(SS,SB),blk,0,stream>>>(sc2, cq_w, cq_b, nw_kq, qbuf, BSD, 0);

  mgemm_k<false,true,EPI_SILU,float><<<dim3(64,8,1),blk,0,stream>>>(
      sc1, wg, gb, nullptr, 0.f,0.f, SB*SS, SD, SD, 0,0,0,0, SD,SD,SD,0);
  mgemm_k<false,true,EPI_SILU_MUL,float><<<dim3(64,8,1),blk,0,stream>>>(
      sc1, wb, gb, gb, 0.f,0.f, SB*SS, SD, SD, 0,0,0,0, SD,SD,SD,SD);

  mgemm_k<false,true,EPI_SILU,float><<<dim3(64,8,1),blk,0,stream>>>(
      sc1, wg + (long)SD*SD, nsbuf, nullptr, 0.f,0.f, SB*SS, SD, SD, 0,0,0,0, SD,SD,SD,0);
  chunk_means1_k<<<SB*SNCH, blk, 0, stream>>>(nsbuf, etaM);
  mgemm_k<false,true,EPI_SILU,float><<<dim3(64,8,1),blk,0,stream>>>(
      sc1, wg + 2L*SD*SD, nsbuf, nullptr, 0.f,0.f, SB*SS, SD, SD, 0,0,0,0, SD,SD,SD,0);
  chunk_means1_k<<<SB*SNCH, blk, 0, stream>>>(nsbuf, alphaM);

  copy_f_k<<<256,blk,0,stream>>>(kp, KPBATCH, buf_k, (long)SWIN*SD, (long)SWIN*SD, SB);
  copy_f_k<<<256,blk,0,stream>>>(vp, KPBATCH, buf_v, (long)SWIN*SD, (long)SWIN*SD, SB);
  copy_f_k<<<256,blk,0,stream>>>(Mb, DD, mem0, DD, DD, SB);

  // split once for the scan (AFTER nsbuf is dead)
  split_k<<<512,blk,0,stream>>>(khl, 2*KPBATCH, KPBATCH, kp, KPBATCH, KPBATCH, SB);
  split_k<<<512,blk,0,stream>>>(vhl, 2*KPBATCH, KPBATCH, vp, KPBATCH, KPBATCH, SB);
  split_k<<<512,blk,0,stream>>>(qhl, 2*BSD, BSD, qbuf, BSD, BSD, SB);
  split_k<<<256,blk,0,stream>>>(Mhl, 2*DD, DD, Mb, DD, DD, SB);

  // ================= Phase B: sequential chunk scan (split-pair) =================
  for (int t = 0; t < SNCH; ++t) {
    const long off = (long)t*SCH*SD;
    // err = ck@M - cv  [192,512] -> errhl
    sgemm_k<false,false,EPI_SUB,false,true,false><<<dim3(3,8,2),blk,0,stream>>>(
        khl + off, Mhl, nullptr, errhl, vp + off, nullptr, 0.f,0.f,
        192, 512, 512,
        2*KPBATCH, KPBATCH, 2*DD, DD,
        0, 2*ERRN, ERRN, KPBATCH, 0,
        512,512,512,512);
    // grad = ck^T @ err -> X0 (f32)
    sgemm_k<true,false,EPI_NONE,false,false,true><<<dim3(8,8,2),blk,0,stream>>>(
        khl + off, errhl, X0, nullptr, nullptr, nullptr, 0.f,0.f,
        512, 512, 192,
        2*KPBATCH, KPBATCH, 2*ERRN, ERRN,
        DD, 0, 0, 0, 0,
        512,512,512,0);
    frob_partial_k<<<dim3(32,2),blk,0,stream>>>(X0, partials);
    ns_scale_split_k<<<dim3(64,2),blk,0,stream>>>(X0, partials, Xhl);
    // 5 Newton-Schulz iterations (A = X@X^T symmetric; T symmetric)
    unsigned short* Xc = Xhl; unsigned short* Xn = Yhl;
    for (int it = 0; it < 5; ++it) {
      sgemm_k<false,true,EPI_NONE,false,true,false><<<dim3(8,8,2),blk,0,stream>>>(
          Xc, Xc, nullptr, Ahl, nullptr, nullptr, 0.f,0.f,
          512,512,512, 2*DD,DD, 2*DD,DD, 0, 2*DD,DD, 0,0, 512,512,512,0);
      sgemm_k<false,true,EPI_LINCOMB,true,true,false><<<dim3(8,8,2),blk,0,stream>>>(
          Ahl, Ahl, nullptr, Thl, nullptr, Ahl, -4.7750f, 2.0315f,
          512,512,512, 2*DD,DD, 2*DD,DD, 0, 2*DD,DD, 2*DD,DD, 512,512,512,512);
      sgemm_k<false,false,EPI_LINCOMB,true,true,false><<<dim3(8,8,2),blk,0,stream>>>(
          Thl, Xc, nullptr, Xn, nullptr, Xc, 3.4445f, 1.0f,
          512,512,512, 2*DD,DD, 2*DD,DD, 0, 2*DD,DD, 2*DD,DD, 512,512,512,512);
      unsigned short* tmp = Xc; Xc = Xn; Xn = tmp;
    }
    update_Mp_k<<<2048,blk,0,stream>>>(Mhl, Xc, etaM, alphaM, t);
    // out_chunk = cq @ M -> aout f32
    sgemm_k<false,false,EPI_NONE,false,false,true><<<dim3(1,8,2),blk,0,stream>>>(
        qhl + off, Mhl, aout + off, nullptr, nullptr, nullptr, 0.f,0.f,
        64, 512, 512,
        2*BSD, BSD, 2*DD, DD,
        BSD, 0, 0, 0, 0,
        512,512,512,0);
  }

  // ================= Phase C =================
  atlas_final_norm_k<<<SB*SS,blk,0,stream>>>(sc2, gb, nw_out, n1_w);

  // side outputs (before kp/vp reuse)
  merge_k<<<256,blk,0,stream>>>(ob + (long)SB*SS*SD, DD, Mhl, 2*DD, DD, DD, SB);
  copy_f_k<<<256,blk,0,stream>>>(ob + (long)SB*SS*SD + SB*DD, (long)SWIN*SD,
      kp + (long)SS*SD, KPBATCH, (long)SWIN*SD, SB);
  copy_f_k<<<256,blk,0,stream>>>(ob + (long)SB*SS*SD + SB*DD + (long)SB*SWIN*SD, (long)SWIN*SD,
      vp + (long)SS*SD, KPBATCH, (long)SWIN*SD, SB);

  // SWA 1 on x
  mgemm_k<false,true,EPI_NONE,float><<<dim3(64,8,1),blk,0,stream>>>(
      x, s1_wq, sc1, nullptr,0.f,0.f, SB*SS, SD, SD, 0,0,0,0, SD,SD,SD,0);
  mgemm_k<false,true,EPI_NONE,float><<<dim3(64,8,1),blk,0,stream>>>(
      x, s1_wk, gb, nullptr,0.f,0.f, SB*SS, SD, SD, 0,0,0,0, SD,SD,SD,0);
  mgemm_k<false,true,EPI_NONE,float><<<dim3(64,8,1),blk,0,stream>>>(
      x, s1_wv, qbuf, nullptr,0.f,0.f, SB*SS, SD, SD, 0,0,0,0, SD,SD,SD,0);
  attn_swa_k<<<SB*SH*SS/4, blk, 0, stream>>>(sc1, gb, qbuf, kp);
  mgemm_k<false,true,EPI_NONE,float><<<dim3(64,8,1),blk,0,stream>>>(
      kp, s1_wo, vp, nullptr,0.f,0.f, SB*SS, SD, SD, 0,0,0,0, SD,SD,SD,0);
  rms_add_k<<<SB*SS,blk,0,stream>>>(vp, n2_w, sc2);   // sc2 = fused

  // SWA 2 on fused
  mgemm_k<false,true,EPI_NONE,float><<<dim3(64,8,1),blk,0,stream>>>(
      sc2, s2_wq, sc1, nullptr,0.f,0.f, SB*SS, SD, SD, 0,0,0,0, SD,SD,SD,0);
  mgemm_k<false,true,EPI_NONE,float><<<dim3(64,8,1),blk,0,stream>>>(
      sc2, s2_wk, gb, nullptr,0.f,0.f, SB*SS, SD, SD, 0,0,0,0, SD,SD,SD,0);
  mgemm_k<false,true,EPI_NONE,float><<<dim3(64,8,1),blk,0,stream>>>(
      sc2, s2_wv, qbuf, nullptr,0.f,0.f, SB*SS, SD, SD, 0,0,0,0, SD,SD,SD,0);
  attn_swa_k<<<SB*SH*SS/4, blk, 0, stream>>>(sc1, gb, qbuf, kp);
  mgemm_k<false,true,EPI_NONE,float><<<dim3(64,8,1),blk,0,stream>>>(
      kp, s2_wo, sc1, nullptr,0.f,0.f, SB*SS, SD, SD, 0,0,0,0, SD,SD,SD,0); // y=sc1

  // MLP
  mgemm_k<false,true,EPI_SILU,float><<<dim3(64,32,1),blk,0,stream>>>(
      sc1, m_w1, hbuf, nullptr,0.f,0.f, SB*SS, SFF, SD, 0,0,0,0, SD,SD,SFF,0);
  mgemm_k<false,true,EPI_MUL,float><<<dim3(64,32,1),blk,0,stream>>>(
      sc1, m_w2, hbuf, hbuf, 0.f,0.f, SB*SS, SFF, SD, 0,0,0,0, SD,SD,SFF,SFF);
  mgemm_k<false,true,EPI_ADD,float><<<dim3(64,8,1),blk,0,stream>>>(
      hbuf, m_w3, ob, sc2, 0.f,0.f, SB*SS, SD, SFF, 0,0,0,0, SFF,SFF,SD,SD);
}

// Round 8
// 8074.630 us; speedup vs baseline: 3.3921x; 1.2339x over previous
//
#include <hip/hip_runtime.h>
#include <hip/hip_bf16.h>

typedef __hip_bfloat16 bf16;
typedef __attribute__((ext_vector_type(8))) short bfrag;            // 8 bf16 = 4 VGPRs
typedef __attribute__((ext_vector_type(8))) unsigned short u16x8;   // 16B copy unit
typedef __attribute__((ext_vector_type(4))) float f32x4;

#define SB 2
#define SS 2048
#define SD 512
#define SH 8
#define SWIN 128
#define SCH 64
#define SNCH 32
#define SFF 2048
#define KPROWS 2176              // WIN + S
#define KPBATCH 1114112L         // KPROWS*SD
#define BSD 1048576L             // SS*SD
#define DD 262144L               // SD*SD
#define ERRN 98304L              // 192*SD

__device__ __forceinline__ void stf(float* p, float v){ *p = v; }
__device__ __forceinline__ void stf(bf16* p, float v){ *p = __float2bfloat16(v); }

// f32 -> bf16 bits, round-to-nearest-even (finite inputs)
__device__ __forceinline__ unsigned short f2bs(float f){
  union { float f; unsigned int u; } v; v.f = f;
  unsigned int r = v.u + 0x7FFFu + ((v.u >> 16) & 1u);
  return (unsigned short)(r >> 16);
}
__device__ __forceinline__ float bs2f(unsigned short h){
  union { unsigned int u; float f; } v; v.u = ((unsigned int)h) << 16;
  return v.f;
}

__device__ __forceinline__ float block_sum256(float v, float* sbuf){
  #pragma unroll
  for (int o = 32; o > 0; o >>= 1) v += __shfl_xor(v, o);
  int wid = threadIdx.x >> 6;
  if ((threadIdx.x & 63) == 0) sbuf[wid] = v;
  __syncthreads();
  float r = sbuf[0] + sbuf[1] + sbuf[2] + sbuf[3];
  __syncthreads();
  return r;
}

enum { EPI_NONE=0, EPI_SILU=1, EPI_SUB=2, EPI_LINCOMB=3, EPI_MUL=4, EPI_ADD=5, EPI_SILU_MUL=6 };

// ===================== split-pair MFMA GEMM (scan) =====================
// Pre-split bf16 hi/lo planes; 3-term Dekker product, f32 accum.
// BM in {32,64}, BN=64. Double-buffered LDS, reg prefetch, 1 barrier/k-step.
// TRA: A given [K,M]. TRB: B given [N,K]. M%BM==N%64==K%32==0.
template<int BM, bool TRA, bool TRB, int EPI, bool EPAIR, bool OSPLIT, bool OF32, bool FROB>
__global__ __launch_bounds__(256)
void sgemm_k(const unsigned short* __restrict__ Ahl, const unsigned short* __restrict__ Bhl,
             float* __restrict__ Cf, unsigned short* __restrict__ Chl,
             const float* __restrict__ Ef, const unsigned short* __restrict__ Ehl,
             float* __restrict__ frobOut,
             float a0, float a1, int M, int N, int K,
             long sA, long pA, long sB, long pB,
             long sCf, long sChl, long pC, long sE, long pE,
             int lda, int ldb, int ldc, int lde)
{
  constexpr int MR = BM/32;                           // 1 (BM=32) or 2 (BM=64)
  __shared__ __align__(16) unsigned short As[2][2][BM][40];
  __shared__ __align__(16) unsigned short Bs[2][2][64][40];
  __shared__ float fb[4];
  const int bz = blockIdx.z;
  const unsigned short* A = Ahl + (long)bz*sA;
  const unsigned short* B = Bhl + (long)bz*sB;
  const int bm = blockIdx.x*BM, bn = blockIdx.y*64;
  const int tid = threadIdx.x;
  const int lane = tid & 63, wid = tid >> 6;
  const int wr = (wid >> 1)*16*MR, wc = (wid & 1)*32;
  const int fm = lane & 15, fk = (lane >> 4)*8;

  // staging address precompute
  int arow=0, acb=0, ak=0, am0=0, apl=0;
  if (!TRA) {
    if (BM==64){ arow=tid>>2; acb=(tid&3)<<3; }
    else { apl=tid>>7; int v=tid&127; arow=v>>2; acb=(v&3)<<3; }
  } else {
    if (BM==64){ ak=tid>>3; am0=(tid&7)<<3; }
    else { apl=tid>>7; int v=tid&127; ak=v>>2; am0=(v&3)<<3; }
  }
  int brow=0, bcb=0, bk=0, bn0=0;
  if (TRB){ brow=tid>>2; bcb=(tid&3)<<3; } else { bk=tid>>3; bn0=(tid&7)<<3; }

  u16x8 ra0, ra1, rb0, rb1;
  auto LOADA = [&](int k0){
    if (!TRA) {
      const unsigned short* a0 = A + (long)(bm+arow)*lda + k0 + acb;
      if (BM==64){ ra0 = *reinterpret_cast<const u16x8*>(a0);
                   ra1 = *reinterpret_cast<const u16x8*>(a0 + pA); }
      else       { ra0 = *reinterpret_cast<const u16x8*>(a0 + (apl ? pA : 0)); }
    } else {
      const unsigned short* a0 = A + (long)(k0+ak)*lda + bm + am0;
      if (BM==64){ ra0 = *reinterpret_cast<const u16x8*>(a0);
                   ra1 = *reinterpret_cast<const u16x8*>(a0 + pA); }
      else       { ra0 = *reinterpret_cast<const u16x8*>(a0 + (apl ? pA : 0)); }
    }
  };
  auto STOREA = [&](int buf){
    if (!TRA) {
      if (BM==64){ *reinterpret_cast<u16x8*>(&As[buf][0][arow][acb]) = ra0;
                   *reinterpret_cast<u16x8*>(&As[buf][1][arow][acb]) = ra1; }
      else       { *reinterpret_cast<u16x8*>(&As[buf][apl][arow][acb]) = ra0; }
    } else {
      if (BM==64){
        #pragma unroll
        for (int j=0;j<8;j++){ As[buf][0][am0+j][ak]=ra0[j]; As[buf][1][am0+j][ak]=ra1[j]; }
      } else {
        #pragma unroll
        for (int j=0;j<8;j++){ As[buf][apl][am0+j][ak]=ra0[j]; }
      }
    }
  };
  auto LOADB = [&](int k0){
    if (TRB) {
      const unsigned short* b0 = B + (long)(bn+brow)*ldb + k0 + bcb;
      rb0 = *reinterpret_cast<const u16x8*>(b0);
      rb1 = *reinterpret_cast<const u16x8*>(b0 + pB);
    } else {
      const unsigned short* b0 = B + (long)(k0+bk)*ldb + bn + bn0;
      rb0 = *reinterpret_cast<const u16x8*>(b0);
      rb1 = *reinterpret_cast<const u16x8*>(b0 + pB);
    }
  };
  auto STOREB = [&](int buf){
    if (TRB) {
      *reinterpret_cast<u16x8*>(&Bs[buf][0][brow][bcb]) = rb0;
      *reinterpret_cast<u16x8*>(&Bs[buf][1][brow][bcb]) = rb1;
    } else {
      #pragma unroll
      for (int j=0;j<8;j++){ Bs[buf][0][bn0+j][bk]=rb0[j]; Bs[buf][1][bn0+j][bk]=rb1[j]; }
    }
  };

  f32x4 acc[MR][2];
  #pragma unroll
  for (int i=0;i<MR;i++)
    #pragma unroll
    for (int j=0;j<2;j++) acc[i][j] = (f32x4){0.f,0.f,0.f,0.f};

  const int nk = K >> 5;
  LOADA(0); LOADB(0);
  int buf = 0;
  for (int i = 0; i < nk; i++) {
    STOREA(buf); STOREB(buf);
    __syncthreads();
    if (i+1 < nk) { LOADA((i+1)<<5); LOADB((i+1)<<5); }
    bfrag ah[MR], al[MR], bh[2], bl[2];
    #pragma unroll
    for (int m=0;m<MR;m++){
      ah[m] = *reinterpret_cast<const bfrag*>(&As[buf][0][wr + m*16 + fm][fk]);
      al[m] = *reinterpret_cast<const bfrag*>(&As[buf][1][wr + m*16 + fm][fk]);
    }
    #pragma unroll
    for (int j=0;j<2;j++){
      bh[j] = *reinterpret_cast<const bfrag*>(&Bs[buf][0][wc + j*16 + fm][fk]);
      bl[j] = *reinterpret_cast<const bfrag*>(&Bs[buf][1][wc + j*16 + fm][fk]);
    }
    #pragma unroll
    for (int m=0;m<MR;m++)
      #pragma unroll
      for (int j=0;j<2;j++)
        acc[m][j] = __builtin_amdgcn_mfma_f32_16x16x32_bf16(ah[m], bh[j], acc[m][j], 0,0,0);
    #pragma unroll
    for (int m=0;m<MR;m++)
      #pragma unroll
      for (int j=0;j<2;j++)
        acc[m][j] = __builtin_amdgcn_mfma_f32_16x16x32_bf16(ah[m], bl[j], acc[m][j], 0,0,0);
    #pragma unroll
    for (int m=0;m<MR;m++)
      #pragma unroll
      for (int j=0;j<2;j++)
        acc[m][j] = __builtin_amdgcn_mfma_f32_16x16x32_bf16(al[m], bh[j], acc[m][j], 0,0,0);
    buf ^= 1;
  }

  float fs = 0.f;
  #pragma unroll
  for (int i=0;i<MR;i++) {
    #pragma unroll
    for (int j=0;j<2;j++) {
      #pragma unroll
      for (int r=0;r<4;r++) {
        int row = bm + wr + i*16 + (lane>>4)*4 + r;
        int col = bn + wc + j*16 + fm;
        float v = acc[i][j][r];
        if (EPI == EPI_SUB || EPI == EPI_LINCOMB) {
          long eidx = (long)bz*sE + (long)row*lde + col;
          float e = EPAIR ? (bs2f(Ehl[eidx]) + bs2f(Ehl[eidx + pE])) : Ef[eidx];
          if (EPI == EPI_SUB) v = v - e;
          else                v = a0*e + a1*v;
        }
        if (FROB) fs += v*v;
        if (OF32) Cf[(long)bz*sCf + (long)row*ldc + col] = v;
        if (OSPLIT) {
          long cidx = (long)bz*sChl + (long)row*ldc + col;
          unsigned short h = f2bs(v);
          Chl[cidx]      = h;
          Chl[cidx + pC] = f2bs(v - bs2f(h));
        }
      }
    }
  }
  if (FROB) {
    #pragma unroll
    for (int o = 32; o > 0; o >>= 1) fs += __shfl_xor(fs, o);
    if (lane == 0) fb[wid] = fs;
    __syncthreads();
    if (tid == 0)
      frobOut[bz*(gridDim.x*gridDim.y) + blockIdx.x*gridDim.y + blockIdx.y] =
          fb[0]+fb[1]+fb[2]+fb[3];
  }
}

// ===================== f32-input MFMA GEMM (phase A/C, converts in-kernel) =====================
template<bool TRA, bool TRB, int EPI, typename TO>
__global__ __launch_bounds__(256)
void mgemm_k(const float* __restrict__ Ag, const float* __restrict__ Bg, TO* __restrict__ Cg,
             const float* __restrict__ Eg, float a0, float a1,
             int M, int N, int K,
             long sA, long sB, long sC, long sE,
             int lda, int ldb, int ldc, int lde)
{
  __shared__ __align__(16) unsigned short As[2][64][40];
  __shared__ __align__(16) unsigned short Bs[2][64][40];
  const int bz = blockIdx.z;
  const float* A = Ag + (long)bz*sA;
  const float* Bp = Bg + (long)bz*sB;
  TO* C = Cg + (long)bz*sC;
  const float* E = Eg ? (Eg + (long)bz*sE) : nullptr;
  const int bm = blockIdx.x*64, bn = blockIdx.y*64;
  const int tid = threadIdx.x;
  const int lane = tid & 63, wid = tid >> 6;
  const int wr = (wid >> 1)*32, wc = (wid & 1)*32;
  const int fm = lane & 15, fk = (lane >> 4)*8;

  f32x4 acc[2][2];
  #pragma unroll
  for (int i=0;i<2;i++)
    #pragma unroll
    for (int j=0;j<2;j++) acc[i][j] = (f32x4){0.f,0.f,0.f,0.f};

  for (int k0 = 0; k0 < K; k0 += 32) {
    if (!TRA) {
      int k = tid & 31, m0 = tid >> 5;
      #pragma unroll
      for (int u = 0; u < 8; u++) {
        int m = m0 + u*8;
        float f = A[(long)(bm+m)*lda + k0 + k];
        unsigned short h = f2bs(f);
        As[0][m][k] = h;
        As[1][m][k] = f2bs(f - bs2f(h));
      }
    } else {
      int m = tid & 63, kk0 = tid >> 6;
      #pragma unroll
      for (int u = 0; u < 8; u++) {
        int k = kk0 + u*4;
        float f = A[(long)(k0+k)*lda + bm + m];
        unsigned short h = f2bs(f);
        As[0][m][k] = h;
        As[1][m][k] = f2bs(f - bs2f(h));
      }
    }
    if (TRB) {
      int k = tid & 31, n0 = tid >> 5;
      #pragma unroll
      for (int u = 0; u < 8; u++) {
        int n = n0 + u*8;
        float f = Bp[(long)(bn+n)*ldb + k0 + k];
        unsigned short h = f2bs(f);
        Bs[0][n][k] = h;
        Bs[1][n][k] = f2bs(f - bs2f(h));
      }
    } else {
      int n = tid & 63, kk0 = tid >> 6;
      #pragma unroll
      for (int u = 0; u < 8; u++) {
        int k = kk0 + u*4;
        float f = Bp[(long)(k0+k)*ldb + bn + n];
        unsigned short h = f2bs(f);
        Bs[0][n][k] = h;
        Bs[1][n][k] = f2bs(f - bs2f(h));
      }
    }
    __syncthreads();
    bfrag ah0 = *reinterpret_cast<const bfrag*>(&As[0][wr + fm][fk]);
    bfrag ah1 = *reinterpret_cast<const bfrag*>(&As[0][wr + 16 + fm][fk]);
    bfrag bh0 = *reinterpret_cast<const bfrag*>(&Bs[0][wc + fm][fk]);
    bfrag bh1 = *reinterpret_cast<const bfrag*>(&Bs[0][wc + 16 + fm][fk]);
    bfrag al0 = *reinterpret_cast<const bfrag*>(&As[1][wr + fm][fk]);
    bfrag al1 = *reinterpret_cast<const bfrag*>(&As[1][wr + 16 + fm][fk]);
    bfrag bl0 = *reinterpret_cast<const bfrag*>(&Bs[1][wc + fm][fk]);
    bfrag bl1 = *reinterpret_cast<const bfrag*>(&Bs[1][wc + 16 + fm][fk]);
    acc[0][0] = __builtin_amdgcn_mfma_f32_16x16x32_bf16(ah0, bh0, acc[0][0], 0,0,0);
    acc[0][1] = __builtin_amdgcn_mfma_f32_16x16x32_bf16(ah0, bh1, acc[0][1], 0,0,0);
    acc[1][0] = __builtin_amdgcn_mfma_f32_16x16x32_bf16(ah1, bh0, acc[1][0], 0,0,0);
    acc[1][1] = __builtin_amdgcn_mfma_f32_16x16x32_bf16(ah1, bh1, acc[1][1], 0,0,0);
    acc[0][0] = __builtin_amdgcn_mfma_f32_16x16x32_bf16(ah0, bl0, acc[0][0], 0,0,0);
    acc[0][1] = __builtin_amdgcn_mfma_f32_16x16x32_bf16(ah0, bl1, acc[0][1], 0,0,0);
    acc[1][0] = __builtin_amdgcn_mfma_f32_16x16x32_bf16(ah1, bl0, acc[1][0], 0,0,0);
    acc[1][1] = __builtin_amdgcn_mfma_f32_16x16x32_bf16(ah1, bl1, acc[1][1], 0,0,0);
    acc[0][0] = __builtin_amdgcn_mfma_f32_16x16x32_bf16(al0, bh0, acc[0][0], 0,0,0);
    acc[0][1] = __builtin_amdgcn_mfma_f32_16x16x32_bf16(al0, bh1, acc[0][1], 0,0,0);
    acc[1][0] = __builtin_amdgcn_mfma_f32_16x16x32_bf16(al1, bh0, acc[1][0], 0,0,0);
    acc[1][1] = __builtin_amdgcn_mfma_f32_16x16x32_bf16(al1, bh1, acc[1][1], 0,0,0);
    __syncthreads();
  }

  #pragma unroll
  for (int i=0;i<2;i++) {
    #pragma unroll
    for (int j=0;j<2;j++) {
      #pragma unroll
      for (int r=0;r<4;r++) {
        int row = bm + wr + i*16 + (lane>>4)*4 + r;
        int col = bn + wc + j*16 + fm;
        float v = acc[i][j][r];
        if (EPI == EPI_SILU)          v = v / (1.f + __expf(-v));
        else if (EPI == EPI_SUB)      v = v - E[(long)row*lde + col];
        else if (EPI == EPI_LINCOMB)  v = a0*E[(long)row*lde + col] + a1*v;
        else if (EPI == EPI_MUL)      v = v * E[(long)row*lde + col];
        else if (EPI == EPI_ADD)      v = v + E[(long)row*lde + col];
        else if (EPI == EPI_SILU_MUL) v = (v / (1.f + __expf(-v))) * E[(long)row*lde + col];
        stf(&C[(long)row*ldc + col], v);
      }
    }
  }
}

// xn = x * nw * rsqrt(mean(x^2)+eps); one block per row
__global__ __launch_bounds__(256) void rmsnorm_in_k(const float* __restrict__ x,
    const float* __restrict__ w, float* __restrict__ xn)
{
  __shared__ float sbuf[4];
  long row = blockIdx.x;
  const float* xr = x + row*SD;
  int c0 = threadIdx.x, c1 = threadIdx.x + 256;
  float v0 = xr[c0], v1 = xr[c1];
  float ss = block_sum256(v0*v0 + v1*v1, sbuf);
  float r = rsqrtf(ss*(1.f/SD) + 1e-6f);
  xn[row*SD + c0] = v0*r*w[c0];
  xn[row*SD + c1] = v1*r*w[c1];
}

// dst_row = rms(silu(dwconv3(raw_row))) * nw ;  one block per (t, b)
__global__ __launch_bounds__(256) void conv_silu_rms_k(const float* __restrict__ raw,
    const float* __restrict__ cw, const float* __restrict__ cb, const float* __restrict__ nw,
    float* __restrict__ dst, long dstBatchStride, int dstRowOff)
{
  __shared__ float sbuf[4];
  int t = blockIdx.x, b = blockIdx.y;
  const float* base = raw + ((long)b*SS + t)*SD;
  float vals[2];
  #pragma unroll
  for (int u = 0; u < 2; u++) {
    int c = threadIdx.x + u*256;
    float w0 = cw[c*3+0], w1 = cw[c*3+1], w2 = cw[c*3+2];
    float acc = cb[c];
    if (t > 0)     acc += base[c - SD]*w0;
    acc += base[c]*w1;
    if (t < SS-1)  acc += base[c + SD]*w2;
    vals[u] = acc / (1.f + __expf(-acc));
  }
  float ss = block_sum256(vals[0]*vals[0] + vals[1]*vals[1], sbuf);
  float r = rsqrtf(ss*(1.f/SD) + 1e-6f);
  float* out = dst + (long)b*dstBatchStride + (long)(dstRowOff + t)*SD;
  out[threadIdx.x]       = vals[0]*r*nw[threadIdx.x];
  out[threadIdx.x + 256] = vals[1]*r*nw[threadIdx.x + 256];
}

// per-(b,chunk) column means of a [B*S, 512] buffer -> [B*NCH, 512]
__global__ __launch_bounds__(256) void chunk_means1_k(const float* __restrict__ src,
    float* __restrict__ dst)
{
  int cb = blockIdx.x;
  long rowbase = (long)cb*SCH*SD;
  #pragma unroll
  for (int u = 0; u < 2; u++) {
    int col = threadIdx.x + u*256;
    float s = 0.f;
    for (int r = 0; r < SCH; r++) s += src[rowbase + (long)r*SD + col];
    dst[(long)cb*SD + col] = s * (1.f/SCH);
  }
}

// X0 *= 1/(||G||_F+1e-7) using 128 per-block slots; write split pair -> Xhl
__global__ __launch_bounds__(256) void ns_scale_split_k(const float* __restrict__ X,
    const float* __restrict__ part, unsigned short* __restrict__ Xhl)
{
  int b = blockIdx.y;
  float s = 0.f;
  for (int i = 0; i < 128; i++) s += part[b*128 + i];
  float scale = 1.f / (sqrtf(s) + 1e-7f);
  long base  = (long)b*DD + (long)blockIdx.x*4096;
  long obase = (long)b*2*DD + (long)blockIdx.x*4096;
  for (int i = threadIdx.x; i < 4096; i += 256) {
    float f = X[base + i] * scale;
    unsigned short h = f2bs(f);
    Xhl[obase + i]      = h;
    Xhl[obase + DD + i] = f2bs(f - bs2f(h));
  }
}

// M = M*alpha - X*eta on split pairs
__global__ __launch_bounds__(256) void update_Mp_k(unsigned short* __restrict__ Mhl,
    const unsigned short* __restrict__ Xhl, const float* __restrict__ etaM,
    const float* __restrict__ alphaM, int chunk)
{
  long idx = (long)blockIdx.x*256 + threadIdx.x;   // 524288 total = B*DD
  int b = (int)(idx >> 18);
  long r = idx & (DD-1);
  int col = (int)(idx & (SD-1));
  long mo = ((long)(b*32 + chunk) << 9) + col;
  long pb = (long)b*2*DD + r;
  float m  = bs2f(Mhl[pb]) + bs2f(Mhl[pb + DD]);
  float xv = bs2f(Xhl[pb]) + bs2f(Xhl[pb + DD]);
  float v = m*alphaM[mo] - xv*etaM[mo];
  unsigned short h = f2bs(v);
  Mhl[pb]      = h;
  Mhl[pb + DD] = f2bs(v - bs2f(h));
}

// atlas epilogue (in place): t = rms(a)*nw_out*gb; a = rms(t)*n1_w
__global__ __launch_bounds__(256) void atlas_final_norm_k(float* __restrict__ a,
    const float* __restrict__ gb, const float* __restrict__ nwout,
    const float* __restrict__ n1w)
{
  __shared__ float sbuf[4];
  long row = blockIdx.x;
  float* xr = a + row*SD;
  int c0 = threadIdx.x, c1 = threadIdx.x + 256;
  float v0 = xr[c0], v1 = xr[c1];
  float ss = block_sum256(v0*v0 + v1*v1, sbuf);
  float r = rsqrtf(ss*(1.f/SD) + 1e-6f);
  float t0 = v0*r*nwout[c0] * gb[row*SD+c0];
  float t1 = v1*r*nwout[c1] * gb[row*SD+c1];
  float ss2 = block_sum256(t0*t0 + t1*t1, sbuf);
  float r2 = rsqrtf(ss2*(1.f/SD) + 1e-6f);
  xr[c0] = t0*r2*n1w[c0];
  xr[c1] = t1*r2*n1w[c1];
}

// dst = rms(o)*w + dst  (in place on dst)
__global__ __launch_bounds__(256) void rms_add_k(const float* __restrict__ o,
    const float* __restrict__ w, float* __restrict__ dst)
{
  __shared__ float sbuf[4];
  long row = blockIdx.x;
  const float* xr = o + row*SD;
  int c0 = threadIdx.x, c1 = threadIdx.x + 256;
  float v0 = xr[c0], v1 = xr[c1];
  float ss = block_sum256(v0*v0 + v1*v1, sbuf);
  float r = rsqrtf(ss*(1.f/SD) + 1e-6f);
  dst[row*SD+c0] += v0*r*w[c0];
  dst[row*SD+c1] += v1*r*w[c1];
}

// sliding-window attention, one wave per (b, h, query); 4 waves/block
__global__ __launch_bounds__(256) void attn_swa_k(const float* __restrict__ Q,
    const float* __restrict__ K, const float* __restrict__ V, float* __restrict__ O)
{
  __shared__ float sc[4][SWIN];
  int wid = threadIdx.x >> 6, lane = threadIdx.x & 63;
  int w = blockIdx.x*4 + wid;
  int b = w >> 14;
  int rem = w & 16383;
  int h = rem >> 11;
  int i = rem & (SS-1);
  const float* qp = Q + ((long)b*SS + i)*SD + h*64;
  float qv = qp[lane];
  int j0 = i - (SWIN-1); if (j0 < 0) j0 = 0;
  int cnt = i - j0 + 1;
  const float* Kb = K + (long)b*SS*SD + h*64;
  const float* Vb = V + (long)b*SS*SD + h*64;
  float mx = -1e30f;
  for (int jj = 0; jj < cnt; jj++) {
    float p = qv * Kb[(long)(j0+jj)*SD + lane];
    #pragma unroll
    for (int o2 = 32; o2 > 0; o2 >>= 1) p += __shfl_xor(p, o2);
    p *= 0.125f;
    if (lane == 0) sc[wid][jj] = p;
    mx = fmaxf(mx, p);
  }
  __syncthreads();
  float sum = 0.f, oa = 0.f;
  for (int jj = 0; jj < cnt; jj++) {
    float p = __expf(sc[wid][jj] - mx);
    sum += p;
    oa += p * Vb[(long)(j0+jj)*SD + lane];
  }
  O[((long)b*SS + i)*SD + h*64 + lane] = oa / sum;
}

__global__ __launch_bounds__(256) void copy_f_k(float* __restrict__ dst, long dstride,
    const float* __restrict__ src, long sstride, long nper, int nb)
{
  long total = nper * nb;
  for (long i = (long)blockIdx.x*256 + threadIdx.x; i < total; i += (long)gridDim.x*256) {
    long b = i / nper, r = i - b*nper;
    dst[b*dstride + r] = src[b*sstride + r];
  }
}

// f32 -> hi/lo bf16 planes
__global__ __launch_bounds__(256) void split_k(unsigned short* __restrict__ dst,
    long dBatch, long dPlane, const float* __restrict__ src, long sBatch,
    long nper, int nb)
{
  long total = nper * nb;
  for (long i = (long)blockIdx.x*256 + threadIdx.x; i < total; i += (long)gridDim.x*256) {
    long b = i / nper, r = i - b*nper;
    float f = src[b*sBatch + r];
    unsigned short h = f2bs(f);
    dst[b*dBatch + r]          = h;
    dst[b*dBatch + dPlane + r] = f2bs(f - bs2f(h));
  }
}

// hi/lo planes -> f32
__global__ __launch_bounds__(256) void merge_k(float* __restrict__ dst, long dBatch,
    const unsigned short* __restrict__ src, long sBatch, long sPlane, long nper, int nb)
{
  long total = nper * nb;
  for (long i = (long)blockIdx.x*256 + threadIdx.x; i < total; i += (long)gridDim.x*256) {
    long b = i / nper, r = i - b*nper;
    dst[b*dBatch + r] = bs2f(src[b*sBatch + r]) + bs2f(src[b*sBatch + sPlane + r]);
  }
}

extern "C" void kernel_launch(void* const* d_in, const int* in_sizes, int n_in,
                              void* d_out, int out_size, void* d_ws, size_t ws_size,
                              hipStream_t stream)
{
  (void)in_sizes; (void)n_in; (void)out_size; (void)ws_size;
  const float* x      = (const float*)d_in[0];
  const float* mem0   = (const float*)d_in[1];
  const float* buf_k  = (const float*)d_in[2];
  const float* buf_v  = (const float*)d_in[3];
  const float* nw_in  = (const float*)d_in[4];
  const float* nw_kq  = (const float*)d_in[5];
  const float* nw_out = (const float*)d_in[6];
  const float* wk_a   = (const float*)d_in[7];
  const float* wq_a   = (const float*)d_in[8];
  const float* wv_a   = (const float*)d_in[9];
  const float* wg     = (const float*)d_in[10];
  const float* wb     = (const float*)d_in[11];
  const float* ck_w   = (const float*)d_in[12];
  const float* ck_b   = (const float*)d_in[13];
  const float* cq_w   = (const float*)d_in[14];
  const float* cq_b   = (const float*)d_in[15];
  const float* s1_wq  = (const float*)d_in[16];
  const float* s1_wk  = (const float*)d_in[17];
  const float* s1_wv  = (const float*)d_in[18];
  const float* s1_wo  = (const float*)d_in[19];
  const float* s2_wq  = (const float*)d_in[20];
  const float* s2_wk  = (const float*)d_in[21];
  const float* s2_wv  = (const float*)d_in[22];
  const float* s2_wo  = (const float*)d_in[23];
  const float* n1_w   = (const float*)d_in[24];
  const float* n2_w   = (const float*)d_in[25];
  const float* m_w1   = (const float*)d_in[26];
  const float* m_w2   = (const float*)d_in[27];
  const float* m_w3   = (const float*)d_in[28];
  float* ob = (float*)d_out;

  // ---- workspace carve: f32 section (~56MB) + u16 split arena (~38MB) ----
  float* p = (float*)d_ws;
  float* kp   = p; p += SB*KPBATCH;   // padded k f32; C: attn out; MLP: h1 head
  float* vp   = p; p += SB*KPBATCH;   // padded v f32; C: oproj1 out
  float* qbuf = p; p += SB*BSD;       // atlas q f32; C: v1/v2
  float* gb   = p; p += SB*BSD;       // gamma*bypass; C: k1/k2; MLP: h1 tail
  float* sc1  = p; p += SB*BSD;       // xn; C: q1/q2, y
  float* sc2  = p; p += SB*BSD;       // kraw/qraw; B: aout; C: memn->fused
  float* Mb   = p; p += SB*DD;        // mem0 f32 (split source)
  float* X0   = p; p += SB*DD;        // grad f32 (frob input)
  float* etaM = p; p += (long)SB*SNCH*SD;
  float* alphaM = p; p += (long)SB*SNCH*SD;
  float* partials = p; p += 512;
  unsigned short* us = (unsigned short*)p;
  unsigned short* khl = us; us += SB*2*KPBATCH;
  unsigned short* vhl = us; us += SB*2*KPBATCH;
  unsigned short* qhl = us; us += SB*2*BSD;
  unsigned short* Mhl = us; us += SB*2*DD;
  unsigned short* Xhl = us; us += SB*2*DD;
  unsigned short* Yhl = us; us += SB*2*DD;
  unsigned short* Ahl = us; us += SB*2*DD;
  unsigned short* Thl = us; us += SB*2*DD;
  unsigned short* errhl = us; us += SB*2*ERRN;
  float* nsbuf = (float*)khl;         // phase-A scratch (before splits)
  float* aout = sc2;
  float* hbuf = kp;                   // MLP h1/h2: kp..gb span

  dim3 blk(256);

  // ================= Phase A =================
  rmsnorm_in_k<<<SB*SS, blk, 0, stream>>>(x, nw_in, sc1);

  mgemm_k<false,true,EPI_SILU,float><<<dim3(32,8,2),blk,0,stream>>>(
      sc1, wv_a, vp + (long)SWIN*SD, nullptr, 0.f,0.f, SS, SD, SD,
      BSD, 0, KPBATCH, 0, SD, SD, SD, 0);

  mgemm_k<false,true,EPI_NONE,float><<<dim3(64,8,1),blk,0,stream>>>(
      sc1, wk_a, sc2, nullptr, 0.f,0.f, SB*SS, SD, SD, 0,0,0,0, SD,SD,SD,0);
  conv_silu_rms_k<<<dim3(SS,SB),blk,0,stream>>>(sc2, ck_w, ck_b, nw_kq, kp, KPBATCH, SWIN);

  mgemm_k<false,true,EPI_NONE,float><<<dim3(64,8,1),blk,0,stream>>>(
      sc1, wq_a, sc2, nullptr, 0.f,0.f, SB*SS, SD, SD, 0,0,0,0, SD,SD,SD,0);
  conv_silu_rms_k<<<dim3(SS,SB),blk,0,stream>>>(sc2, cq_w, cq_b, nw_kq, qbuf, BSD, 0);

  mgemm_k<false,true,EPI_SILU,float><<<dim3(64,8,1),blk,0,stream>>>(
      sc1, wg, gb, nullptr, 0.f,0.f, SB*SS, SD, SD, 0,0,0,0, SD,SD,SD,0);
  mgemm_k<false,true,EPI_SILU_MUL,float><<<dim3(64,8,1),blk,0,stream>>>(
      sc1, wb, gb, gb, 0.f,0.f, SB*SS, SD, SD, 0,0,0,0, SD,SD,SD,SD);

  mgemm_k<false,true,EPI_SILU,float><<<dim3(64,8,1),blk,0,stream>>>(
      sc1, wg + (long)SD*SD, nsbuf, nullptr, 0.f,0.f, SB*SS, SD, SD, 0,0,0,0, SD,SD,SD,0);
  chunk_means1_k<<<SB*SNCH, blk, 0, stream>>>(nsbuf, etaM);
  mgemm_k<false,true,EPI_SILU,float><<<dim3(64,8,1),blk,0,stream>>>(
      sc1, wg + 2L*SD*SD, nsbuf, nullptr, 0.f,0.f, SB*SS, SD, SD, 0,0,0,0, SD,SD,SD,0);
  chunk_means1_k<<<SB*SNCH, blk, 0, stream>>>(nsbuf, alphaM);

  copy_f_k<<<256,blk,0,stream>>>(kp, KPBATCH, buf_k, (long)SWIN*SD, (long)SWIN*SD, SB);
  copy_f_k<<<256,blk,0,stream>>>(vp, KPBATCH, buf_v, (long)SWIN*SD, (long)SWIN*SD, SB);
  copy_f_k<<<256,blk,0,stream>>>(Mb, DD, mem0, DD, DD, SB);

  // split once for the scan (AFTER nsbuf is dead)
  split_k<<<512,blk,0,stream>>>(khl, 2*KPBATCH, KPBATCH, kp, KPBATCH, KPBATCH, SB);
  split_k<<<512,blk,0,stream>>>(vhl, 2*KPBATCH, KPBATCH, vp, KPBATCH, KPBATCH, SB);
  split_k<<<512,blk,0,stream>>>(qhl, 2*BSD, BSD, qbuf, BSD, BSD, SB);
  split_k<<<256,blk,0,stream>>>(Mhl, 2*DD, DD, Mb, DD, DD, SB);

  // ================= Phase B: sequential chunk scan (split-pair) =================
  for (int t = 0; t < SNCH; ++t) {
    const long off = (long)t*SCH*SD;
    // err = ck@M - cv  [192,512] -> errhl
    sgemm_k<32,false,false,EPI_SUB,false,true,false,false><<<dim3(6,8,2),blk,0,stream>>>(
        khl + off, Mhl, nullptr, errhl, vp + off, nullptr, nullptr, 0.f,0.f,
        192, 512, 512,
        2*KPBATCH, KPBATCH, 2*DD, DD,
        0, 2*ERRN, ERRN, KPBATCH, 0,
        512,512,512,512);
    // grad = ck^T @ err -> X0 (f32) + fused Frobenius partials
    sgemm_k<32,true,false,EPI_NONE,false,false,true,true><<<dim3(16,8,2),blk,0,stream>>>(
        khl + off, errhl, X0, nullptr, nullptr, nullptr, partials, 0.f,0.f,
        512, 512, 192,
        2*KPBATCH, KPBATCH, 2*ERRN, ERRN,
        DD, 0, 0, 0, 0,
        512,512,512,0);
    ns_scale_split_k<<<dim3(64,2),blk,0,stream>>>(X0, partials, Xhl);
    // 5 Newton-Schulz iterations
    unsigned short* Xc = Xhl; unsigned short* Xn = Yhl;
    for (int it = 0; it < 5; ++it) {
      sgemm_k<32,false,true,EPI_NONE,false,true,false,false><<<dim3(16,8,2),blk,0,stream>>>(
          Xc, Xc, nullptr, Ahl, nullptr, nullptr, nullptr, 0.f,0.f,
          512,512,512, 2*DD,DD, 2*DD,DD, 0, 2*DD,DD, 0,0, 512,512,512,0);
      sgemm_k<32,false,true,EPI_LINCOMB,true,true,false,false><<<dim3(16,8,2),blk,0,stream>>>(
          Ahl, Ahl, nullptr, Thl, nullptr, Ahl, nullptr, -4.7750f, 2.0315f,
          512,512,512, 2*DD,DD, 2*DD,DD, 0, 2*DD,DD, 2*DD,DD, 512,512,512,512);
      sgemm_k<32,false,false,EPI_LINCOMB,true,true,false,false><<<dim3(16,8,2),blk,0,stream>>>(
          Thl, Xc, nullptr, Xn, nullptr, Xc, nullptr, 3.4445f, 1.0f,
          512,512,512, 2*DD,DD, 2*DD,DD, 0, 2*DD,DD, 2*DD,DD, 512,512,512,512);
      unsigned short* tmp = Xc; Xc = Xn; Xn = tmp;
    }
    update_Mp_k<<<2048,blk,0,stream>>>(Mhl, Xc, etaM, alphaM, t);
    // out_chunk = cq @ M -> aout f32
    sgemm_k<32,false,false,EPI_NONE,false,false,true,false><<<dim3(2,8,2),blk,0,stream>>>(
        qhl + off, Mhl, aout + off, nullptr, nullptr, nullptr, nullptr, 0.f,0.f,
        64, 512, 512,
        2*BSD, BSD, 2*DD, DD,
        BSD, 0, 0, 0, 0,
        512,512,512,0);
  }

  // ================= Phase C =================
  atlas_final_norm_k<<<SB*SS,blk,0,stream>>>(sc2, gb, nw_out, n1_w);

  // side outputs (before kp/vp reuse)
  merge_k<<<256,blk,0,stream>>>(ob + (long)SB*SS*SD, DD, Mhl, 2*DD, DD, DD, SB);
  copy_f_k<<<256,blk,0,stream>>>(ob + (long)SB*SS*SD + SB*DD, (long)SWIN*SD,
      kp + (long)SS*SD, KPBATCH, (long)SWIN*SD, SB);
  copy_f_k<<<256,blk,0,stream>>>(ob + (long)SB*SS*SD + SB*DD + (long)SB*SWIN*SD, (long)SWIN*SD,
      vp + (long)SS*SD, KPBATCH, (long)SWIN*SD, SB);

  // SWA 1 on x
  mgemm_k<false,true,EPI_NONE,float><<<dim3(64,8,1),blk,0,stream>>>(
      x, s1_wq, sc1, nullptr,0.f,0.f, SB*SS, SD, SD, 0,0,0,0, SD,SD,SD,0);
  mgemm_k<false,true,EPI_NONE,float><<<dim3(64,8,1),blk,0,stream>>>(
      x, s1_wk, gb, nullptr,0.f,0.f, SB*SS, SD, SD, 0,0,0,0, SD,SD,SD,0);
  mgemm_k<false,true,EPI_NONE,float><<<dim3(64,8,1),blk,0,stream>>>(
      x, s1_wv, qbuf, nullptr,0.f,0.f, SB*SS, SD, SD, 0,0,0,0, SD,SD,SD,0);
  attn_swa_k<<<SB*SH*SS/4, blk, 0, stream>>>(sc1, gb, qbuf, kp);
  mgemm_k<false,true,EPI_NONE,float><<<dim3(64,8,1),blk,0,stream>>>(
      kp, s1_wo, vp, nullptr,0.f,0.f, SB*SS, SD, SD, 0,0,0,0, SD,SD,SD,0);
  rms_add_k<<<SB*SS,blk,0,stream>>>(vp, n2_w, sc2);   // sc2 = fused

  // SWA 2 on fused
  mgemm_k<false,true,EPI_NONE,float><<<dim3(64,8,1),blk,0,stream>>>(
      sc2, s2_wq, sc1, nullptr,0.f,0.f, SB*SS, SD, SD, 0,0,0,0, SD,SD,SD,0);
  mgemm_k<false,true,EPI_NONE,float><<<dim3(64,8,1),blk,0,stream>>>(
      sc2, s2_wk, gb, nullptr,0.f,0.f, SB*SS, SD, SD, 0,0,0,0, SD,SD,SD,0);
  mgemm_k<false,true,EPI_NONE,float><<<dim3(64,8,1),blk,0,stream>>>(
      sc2, s2_wv, qbuf, nullptr,0.f,0.f, SB*SS, SD, SD, 0,0,0,0, SD,SD,SD,0);
  attn_swa_k<<<SB*SH*SS/4, blk, 0, stream>>>(sc1, gb, qbuf, kp);
  mgemm_k<false,true,EPI_NONE,float><<<dim3(64,8,1),blk,0,stream>>>(
      kp, s2_wo, sc1, nullptr,0.f,0.f, SB*SS, SD, SD, 0,0,0,0, SD,SD,SD,0); // y=sc1

  // MLP
  mgemm_k<false,true,EPI_SILU,float><<<dim3(64,32,1),blk,0,stream>>>(
      sc1, m_w1, hbuf, nullptr,0.f,0.f, SB*SS, SFF, SD, 0,0,0,0, SD,SD,SFF,0);
  mgemm_k<false,true,EPI_MUL,float><<<dim3(64,32,1),blk,0,stream>>>(
      sc1, m_w2, hbuf, hbuf, 0.f,0.f, SB*SS, SFF, SD, 0,0,0,0, SD,SD,SFF,SFF);
  mgemm_k<false,true,EPI_ADD,float><<<dim3(64,8,1),blk,0,stream>>>(
      hbuf, m_w3, ob, sc2, 0.f,0.f, SB*SS, SD, SFF, 0,0,0,0, SFF,SFF,SD,SD);
}